// Round 6
// baseline (1357.979 us; speedup 1.0000x reference)
//
#include <hip/hip_runtime.h>
#include <stdint.h>

#define NN 50000
#define NE 800000
#define NBLK 196   // ceil(NN/256)

typedef float f32x4 __attribute__((ext_vector_type(4)));
typedef short s16x8 __attribute__((ext_vector_type(8)));

__device__ __forceinline__ float bf2f(unsigned short u) {
    union { unsigned int i; float f; } v; v.i = ((unsigned int)u) << 16; return v.f;
}
__device__ __forceinline__ unsigned short f2bf(float x) {
    union { float f; unsigned int i; } v; v.f = x;
    unsigned int r = v.i + 0x7FFFu + ((v.i >> 16) & 1u);
    return (unsigned short)(r >> 16);
}

// ---------------- graph preprocessing ----------------

__global__ void k_deg(const int* __restrict__ src, const int* __restrict__ dst,
                      int* __restrict__ dego, int* __restrict__ degi) {
    int e = blockIdx.x * 256 + threadIdx.x;
    if (e < NE) {
        atomicAdd(&dego[src[e]], 1);
        atomicAdd(&degi[dst[e]], 1);
    }
}

// parallel exclusive scan of deg_i (3 phases); scanC also computes norms
__global__ void k_scanA(const int* __restrict__ deg, int* __restrict__ incl,
                        int* __restrict__ bsum) {
    __shared__ int sm[256];
    int t = threadIdx.x, i = blockIdx.x * 256 + t;
    int v = (i < NN) ? deg[i] : 0;
    sm[t] = v;
    __syncthreads();
#pragma unroll
    for (int off = 1; off < 256; off <<= 1) {
        int tv = (t >= off) ? sm[t - off] : 0;
        __syncthreads();
        sm[t] += tv;
        __syncthreads();
    }
    if (i < NN) incl[i] = sm[t];
    if (t == 255) bsum[blockIdx.x] = sm[255];
}

__global__ void k_scanB(const int* __restrict__ bsum, int* __restrict__ boff,
                        int* __restrict__ row_ptr) {
    __shared__ int sm[256];
    int t = threadIdx.x;
    int v = (t < NBLK) ? bsum[t] : 0;
    sm[t] = v;
    __syncthreads();
#pragma unroll
    for (int off = 1; off < 256; off <<= 1) {
        int tv = (t >= off) ? sm[t - off] : 0;
        __syncthreads();
        sm[t] += tv;
        __syncthreads();
    }
    if (t < NBLK) boff[t] = sm[t] - v;  // exclusive
    if (t == 255) row_ptr[NN] = sm[255];
}

__global__ void k_scanC(const int* __restrict__ dego, const int* __restrict__ degi,
                        const int* __restrict__ incl, const int* __restrict__ boff,
                        int* __restrict__ row_ptr, int* __restrict__ cursor,
                        float* __restrict__ ns, float* __restrict__ nd) {
    int i = blockIdx.x * 256 + threadIdx.x;
    if (i < NN) {
        int ex = boff[blockIdx.x] + incl[i] - degi[i];
        row_ptr[i] = ex;
        cursor[i] = ex;
        ns[i] = dego[i] > 0 ? rsqrtf((float)dego[i]) : 0.f;
        nd[i] = degi[i] > 0 ? rsqrtf((float)degi[i]) : 0.f;
    }
}

// fill CSR columns; also emit per-edge weight ewt = ns[src]
__global__ void k_fill(const int* __restrict__ src, const int* __restrict__ dst,
                       const float* __restrict__ ns,
                       int* __restrict__ cursor, int* __restrict__ col_src,
                       float* __restrict__ ewt) {
    int e = blockIdx.x * 256 + threadIdx.x;
    if (e < NE) {
        int s = src[e];
        int slot = atomicAdd(&cursor[dst[e]], 1);
        col_src[slot] = s;
        ewt[slot] = ns[s];
    }
}

// ---------------- weight prep ----------------
// 9 QKV mats [256,256] -> merged hi/lo B^T [768][256] per layer; block 0 of each
// matrix also concats its bias into bdst[3][768].
struct QkvPtrs {
    const float* w[9];
    const float* b[9];
    unsigned short* h[3];
    unsigned short* l[3];
    float* bdst;
};

__global__ void k_wsplit9(QkvPtrs P) {
    int m = blockIdx.y;               // 0..8
    int layer = m / 3, which = m - layer * 3;
    int idx = blockIdx.x * 256 + threadIdx.x;   // 0..65535
    int n = idx >> 8, k = idx & 255;
    float w = P.w[m][(size_t)k * 256 + n];
    unsigned short h = f2bf(w);
    size_t o = (size_t)(which * 256 + n) * 256 + k;
    P.h[layer][o] = h;
    P.l[layer][o] = f2bf(w - bf2f(h));
    if (blockIdx.x == 0)
        P.bdst[layer * 768 + which * 256 + (int)threadIdx.x] = P.b[m][threadIdx.x];
}

// Wm [256,256] / W1 [768,512] / W2 [512,256] -> hi/lo B^T, one dispatch.
struct W3Ptrs { const float* w[3]; unsigned short* h[3]; unsigned short* l[3]; };

__global__ void k_wsplit3(W3Ptrs P) {
    int y = blockIdx.y;               // 0..8: 1 unit Wm, 6 units W1, 2 units W2
    int mi, K, N, sub;
    if (y == 0)      { mi = 0; K = 256; N = 256; sub = 0; }
    else if (y < 7)  { mi = 1; K = 768; N = 512; sub = y - 1; }
    else             { mi = 2; K = 512; N = 256; sub = y - 7; }
    int idx = sub * 65536 + blockIdx.x * 256 + (int)threadIdx.x;
    int n = idx / K, k = idx - n * K;
    float w = P.w[mi][(size_t)k * N + n];
    unsigned short h = f2bf(w);
    P.h[mi][idx] = h;
    P.l[mi][idx] = f2bf(w - bf2f(h));
}

// features fp32 -> bf16
__global__ void k_cvt(const float* __restrict__ in, unsigned short* __restrict__ ob, int n4) {
    int i = blockIdx.x * 256 + threadIdx.x;
    if (i < n4) {
        float4 v = ((const float4*)in)[i];
        ushort4 o;
        o.x = f2bf(v.x); o.y = f2bf(v.y); o.z = f2bf(v.z); o.w = f2bf(v.w);
        ((ushort4*)ob)[i] = o;
    }
}

// ---------------- GCN propagate: y[d] = nd[d] * sum ewt[e] * x[src[e]] ----------------
// x bf16 stride ldx; y bf16 [NN,256]. One wave per node; lane owns 4 cols.

__global__ void k_prop(const unsigned short* __restrict__ xb, int ldx,
                       const int* __restrict__ row_ptr, const int* __restrict__ col_src,
                       const float* __restrict__ ewt, const float* __restrict__ ndv,
                       unsigned short* __restrict__ y) {
    int w = (int)((blockIdx.x * 256 + threadIdx.x) >> 6);
    if (w >= NN) return;
    int lane = threadIdx.x & 63;
    int c = lane * 4;
    float a0 = 0, a1 = 0, a2 = 0, a3 = 0;
    int e0 = row_ptr[w], e1 = row_ptr[w + 1];
    int sv = (e0 < e1) ? col_src[e0] : 0;
    for (int p = e0; p < e1; ++p) {
        int sn = (p + 1 < e1) ? col_src[p + 1] : 0;
        float wv = ewt[p];
        const ushort4 xv = *(const ushort4*)(xb + (size_t)sv * ldx + c);
        a0 += wv * bf2f(xv.x); a1 += wv * bf2f(xv.y);
        a2 += wv * bf2f(xv.z); a3 += wv * bf2f(xv.w);
        sv = sn;
    }
    float sc = ndv[w];
    ushort4 o;
    o.x = f2bf(a0 * sc); o.y = f2bf(a1 * sc); o.z = f2bf(a2 * sc); o.w = f2bf(a3 * sc);
    *(ushort4*)(y + (size_t)w * 256 + c) = o;
}

// ---------------- edge attention ----------------
// QKVb [NN,768] bf16: Q 0-255, K 256-511, V 512-767. One wave per dst node.
// 16-lane group g = head g; lane covers 4 dims. Output bf16 into xo (stride 768).

__global__ void k_attn(const unsigned short* __restrict__ QKVb,
                       const int* __restrict__ row_ptr, const int* __restrict__ col_src,
                       unsigned short* __restrict__ xo) {
    int w = (int)((blockIdx.x * 256 + threadIdx.x) >> 6);
    if (w >= NN) return;
    int lane = threadIdx.x & 63;
    int c = lane * 4;
    const ushort4 qu = *(const ushort4*)(QKVb + (size_t)w * 768 + c);
    float q0 = bf2f(qu.x), q1 = bf2f(qu.y), q2 = bf2f(qu.z), q3 = bf2f(qu.w);
    float v0 = 0, v1 = 0, v2 = 0, v3 = 0, z = 0;
    int e0 = row_ptr[w], e1 = row_ptr[w + 1];
    int sv = (e0 < e1) ? col_src[e0] : 0;
    for (int p = e0; p < e1; ++p) {
        int sn = (p + 1 < e1) ? col_src[p + 1] : 0;
        const ushort4 ku = *(const ushort4*)(QKVb + (size_t)sv * 768 + 256 + c);
        const ushort4 vu = *(const ushort4*)(QKVb + (size_t)sv * 768 + 512 + c);
        float t = q0 * bf2f(ku.x) + q1 * bf2f(ku.y) + q2 * bf2f(ku.z) + q3 * bf2f(ku.w);
        t += __shfl_xor(t, 1);
        t += __shfl_xor(t, 2);
        t += __shfl_xor(t, 4);
        t += __shfl_xor(t, 8);
        float scv = __expf(fminf(fmaxf(t * 0.125f, -10.f), 10.f));
        v0 += scv * bf2f(vu.x); v1 += scv * bf2f(vu.y);
        v2 += scv * bf2f(vu.z); v3 += scv * bf2f(vu.w);
        z += scv;
        sv = sn;
    }
    float inv = 1.f / (z + 1e-6f);
    ushort4 o;
    o.x = f2bf(v0 * inv); o.y = f2bf(v1 * inv);
    o.z = f2bf(v2 * inv); o.w = f2bf(v3 * inv);
    *(ushort4*)(xo + (size_t)w * 768 + c) = o;
}

// ---------------- bf16-A 2-term GEMM: C = bf16(relu(A @ W + b)) ----------------
// A bf16 [M,K] (lda, exactly representable); B = W^T split hi/lo bf16 [N,K].
// acc = A*W_hi + A*W_lo  (weights fp32-accurate, 2 MFMAs per tile-pair).
// 128x128 tile, BK=32, 4 waves (2x2 of 64x64). NITER bcol tiles per block.

template <int NITER>
__global__ __launch_bounds__(256) void k_gemm(
    const unsigned short* __restrict__ A, int lda,
    const unsigned short* __restrict__ Bhi, const unsigned short* __restrict__ Blo,
    const float* __restrict__ bias,
    unsigned short* __restrict__ C, int ldc, int coff, int M, int K) {
    __shared__ unsigned short sA[128][40];
    __shared__ unsigned short sB[2][128][40];
    const int tid = threadIdx.x;
    const int lane = tid & 63;
    const int wid = tid >> 6;
    const int wm = wid & 1, wn = wid >> 1;
    const int fr = lane & 15, kg = lane >> 4;
    const int brow = blockIdx.x * 128;

    for (int it = 0; it < NITER; ++it) {
        const int bcol = (blockIdx.y * NITER + it) * 128;
        f32x4 acc[4][4] = {};

        for (int k0 = 0; k0 < K; k0 += 32) {
#pragma unroll
            for (int rep = 0; rep < 2; ++rep) {
                int s = tid + rep * 256;
                int row = s >> 2, ks = (s & 3) * 8;
                int gr = brow + row;
                uint4 av = make_uint4(0, 0, 0, 0);
                if (gr < M) av = *(const uint4*)(A + (size_t)gr * lda + k0 + ks);
                *(uint4*)&sA[row][ks] = av;
                size_t bbase = (size_t)(bcol + row) * K + k0 + ks;
                *(uint4*)&sB[0][row][ks] = *(const uint4*)(Bhi + bbase);
                *(uint4*)&sB[1][row][ks] = *(const uint4*)(Blo + bbase);
            }
            __syncthreads();
            s16x8 a[4], bh[4], bl[4];
#pragma unroll
            for (int f = 0; f < 4; ++f) {
                a[f] = *(const s16x8*)&sA[wm * 64 + f * 16 + fr][kg * 8];
                bh[f] = *(const s16x8*)&sB[0][wn * 64 + f * 16 + fr][kg * 8];
                bl[f] = *(const s16x8*)&sB[1][wn * 64 + f * 16 + fr][kg * 8];
            }
#pragma unroll
            for (int i = 0; i < 4; ++i)
#pragma unroll
                for (int j = 0; j < 4; ++j) {
                    acc[i][j] = __builtin_amdgcn_mfma_f32_16x16x32_bf16(a[i], bh[j], acc[i][j], 0, 0, 0);
                    acc[i][j] = __builtin_amdgcn_mfma_f32_16x16x32_bf16(a[i], bl[j], acc[i][j], 0, 0, 0);
                }
            __syncthreads();
        }

#pragma unroll
        for (int i = 0; i < 4; ++i) {
#pragma unroll
            for (int j = 0; j < 4; ++j) {
                int colG = bcol + wn * 64 + j * 16 + fr;
                float bb = bias[colG];
#pragma unroll
                for (int r = 0; r < 4; ++r) {
                    int row = brow + wm * 64 + i * 16 + kg * 4 + r;
                    if (row < M) {
                        float v = fmaxf(acc[i][j][r] + bb, 0.f);
                        C[(size_t)row * ldc + coff + colG] = f2bf(v);
                    }
                }
            }
        }
    }
}

// ---------------- final row-dot + sigmoid ----------------

__global__ void k_final(const unsigned short* __restrict__ h2, const float* __restrict__ W3,
                        const float* __restrict__ b3, float* __restrict__ out) {
    int w = (int)((blockIdx.x * 256 + threadIdx.x) >> 6);
    if (w >= NN) return;
    int lane = threadIdx.x & 63;
    ushort4 hu = *(const ushort4*)(h2 + (size_t)w * 256 + lane * 4);
    float4 ww = *(const float4*)(W3 + lane * 4);
    float p = bf2f(hu.x) * ww.x + bf2f(hu.y) * ww.y + bf2f(hu.z) * ww.z + bf2f(hu.w) * ww.w;
    p += __shfl_xor(p, 1);
    p += __shfl_xor(p, 2);
    p += __shfl_xor(p, 4);
    p += __shfl_xor(p, 8);
    p += __shfl_xor(p, 16);
    p += __shfl_xor(p, 32);
    if (lane == 0) out[w] = 1.f / (1.f + __expf(-(p + b3[0])));
}

// sentinel: written iff ws_size too small (diagnosable absmax ~= 0.5, no crash)
__global__ void k_sent(float* __restrict__ out) {
    int i = blockIdx.x * 256 + threadIdx.x;
    if (i < NN) out[i] = 0.5f;
}

// ---------------- launch ----------------

extern "C" void kernel_launch(void* const* d_in, const int* in_sizes, int n_in,
                              void* d_out, int out_size, void* d_ws, size_t ws_size,
                              hipStream_t stream) {
    const float* features = (const float*)d_in[0];
    const int* src = (const int*)d_in[1];
    const int* dst = (const int*)d_in[2];
    const float* Wm = (const float*)d_in[4];
    const float* bm = (const float*)d_in[5];
    const float* W1 = (const float*)d_in[24];
    const float* b1 = (const float*)d_in[25];
    const float* W2 = (const float*)d_in[26];
    const float* b2 = (const float*)d_in[27];
    const float* W3 = (const float*)d_in[28];
    const float* b3 = (const float*)d_in[29];
    float* out = (float*)d_out;

    char* ws = (char*)d_ws;
    size_t off = 0;
    auto alloc = [&](size_t b) -> void* {
        void* p = ws + off;
        off = (off + b + 255) & ~(size_t)255;
        return p;
    };

    int* deg_o = (int*)alloc(NN * 4);   // deg_o and deg_i adjacent: single memset
    int* deg_i = (int*)alloc(NN * 4);
    int* row_ptr = (int*)alloc((NN + 1) * 4);
    int* cursor = (int*)alloc(NN * 4);
    int* col_src = (int*)alloc((size_t)NE * 4);
    float* ewt = (float*)alloc((size_t)NE * 4);
    float* ns = (float*)alloc(NN * 4);
    float* nd = (float*)alloc(NN * 4);
    int* incl = (int*)alloc(NN * 4);
    int* bsum = (int*)alloc(NBLK * 4);
    int* boff = (int*)alloc(NBLK * 4);

    unsigned short* Wmt_h = (unsigned short*)alloc(256 * 256 * 2);
    unsigned short* Wmt_l = (unsigned short*)alloc(256 * 256 * 2);
    unsigned short *Wqkvt_h[3], *Wqkvt_l[3];
    for (int l = 0; l < 3; ++l) {
        Wqkvt_h[l] = (unsigned short*)alloc(768 * 256 * 2);
        Wqkvt_l[l] = (unsigned short*)alloc(768 * 256 * 2);
    }
    float* bqkv = (float*)alloc(3 * 768 * 4);
    unsigned short* W1t_h = (unsigned short*)alloc(512 * 768 * 2);
    unsigned short* W1t_l = (unsigned short*)alloc(512 * 768 * 2);
    unsigned short* W2t_h = (unsigned short*)alloc(256 * 512 * 2);
    unsigned short* W2t_l = (unsigned short*)alloc(256 * 512 * 2);

    unsigned short* fbuf = (unsigned short*)alloc((size_t)NN * 256 * 2);   // 25.6 MB
    unsigned short* QKVb = (unsigned short*)alloc((size_t)NN * 768 * 2);   // 76.8 MB
    unsigned short* y = (unsigned short*)alloc((size_t)NN * 256 * 2);      // 25.6 MB
    unsigned short* xcat = (unsigned short*)alloc((size_t)NN * 768 * 2);   // 76.8 MB

    unsigned short* x0b = xcat;   // [NN,256] packed; dead before attn1 overwrites xcat
    unsigned short* h1 = QKVb;    // [NN,512]; QKVb dead after attn3
    unsigned short* h2 = y;       // [NN,256]; y dead after layer-3 QKV gemm

    (void)in_sizes; (void)n_in; (void)out_size;

    if (off > ws_size) {
        k_sent<<<(NN + 255) / 256, 256, 0, stream>>>(out);
        return;
    }

    // one memset covers adjacent deg_o + deg_i
    hipMemsetAsync(deg_o, 0, (size_t)((char*)deg_i - (char*)deg_o) + NN * 4, stream);
    k_deg<<<(NE + 255) / 256, 256, 0, stream>>>(src, dst, deg_o, deg_i);
    k_scanA<<<NBLK, 256, 0, stream>>>(deg_i, incl, bsum);
    k_scanB<<<1, 256, 0, stream>>>(bsum, boff, row_ptr);
    k_scanC<<<NBLK, 256, 0, stream>>>(deg_o, deg_i, incl, boff, row_ptr, cursor, ns, nd);
    k_fill<<<(NE + 255) / 256, 256, 0, stream>>>(src, dst, ns, cursor, col_src, ewt);

    QkvPtrs qp;
    for (int l = 0; l < 3; ++l) {
        for (int m = 0; m < 3; ++m) {
            qp.w[l * 3 + m] = (const float*)d_in[6 + l * 6 + m * 2];
            qp.b[l * 3 + m] = (const float*)d_in[7 + l * 6 + m * 2];
        }
        qp.h[l] = Wqkvt_h[l];
        qp.l[l] = Wqkvt_l[l];
    }
    qp.bdst = bqkv;
    k_wsplit9<<<dim3(256, 9), 256, 0, stream>>>(qp);

    W3Ptrs wp;
    wp.w[0] = Wm; wp.h[0] = Wmt_h; wp.l[0] = Wmt_l;
    wp.w[1] = W1; wp.h[1] = W1t_h; wp.l[1] = W1t_l;
    wp.w[2] = W2; wp.h[2] = W2t_h; wp.l[2] = W2t_l;
    k_wsplit3<<<dim3(256, 9), 256, 0, stream>>>(wp);

    k_cvt<<<(NN * 64 + 255) / 256, 256, 0, stream>>>(features, fbuf, NN * 64);

    const int MB = (NN + 127) / 128;  // 391
    dim3 g2(MB, 2);

    // x0b = bf16(relu(features @ Wm + bm))
    k_gemm<1><<<g2, 256, 0, stream>>>(fbuf, 256, Wmt_h, Wmt_l, bm,
                                      x0b, 256, 0, NN, 256);

    const unsigned short* xin = x0b;
    int ldx = 256;
    for (int l = 0; l < 3; ++l) {
        k_prop<<<12500, 256, 0, stream>>>(xin, ldx, row_ptr, col_src, ewt, nd, y);
        k_gemm<3><<<g2, 256, 0, stream>>>(y, 256, Wqkvt_h[l], Wqkvt_l[l], bqkv + l * 768,
                                          QKVb, 768, 0, NN, 256);
        k_attn<<<12500, 256, 0, stream>>>(QKVb, row_ptr, col_src, xcat + 256 * l);
        xin = xcat + 256 * l;
        ldx = 768;
    }

    // MLP head
    k_gemm<2><<<g2, 256, 0, stream>>>(xcat, 768, W1t_h, W1t_l, b1,
                                      h1, 512, 0, NN, 768);
    k_gemm<1><<<g2, 256, 0, stream>>>(h1, 512, W2t_h, W2t_l, b2,
                                      h2, 256, 0, NN, 512);
    k_final<<<12500, 256, 0, stream>>>(h2, W3, b3, out);
}

// Round 7
// 1242.292 us; speedup vs baseline: 1.0931x; 1.0931x over previous
//
#include <hip/hip_runtime.h>
#include <stdint.h>

#define NN 50000
#define NE 800000
#define NBLK 196   // ceil(NN/256)

typedef float f32x4 __attribute__((ext_vector_type(4)));
typedef short s16x8 __attribute__((ext_vector_type(8)));

__device__ __forceinline__ float bf2f(unsigned short u) {
    union { unsigned int i; float f; } v; v.i = ((unsigned int)u) << 16; return v.f;
}
__device__ __forceinline__ unsigned short f2bf(float x) {
    union { float f; unsigned int i; } v; v.f = x;
    unsigned int r = v.i + 0x7FFFu + ((v.i >> 16) & 1u);
    return (unsigned short)(r >> 16);
}

// ---------------- graph preprocessing ----------------

__global__ void k_deg(const int* __restrict__ src, const int* __restrict__ dst,
                      int* __restrict__ dego, int* __restrict__ degi) {
    int e = blockIdx.x * 256 + threadIdx.x;
    if (e < NE) {
        atomicAdd(&dego[src[e]], 1);
        atomicAdd(&degi[dst[e]], 1);
    }
}

// parallel exclusive scan of deg_i (3 phases); scanC also computes norms
__global__ void k_scanA(const int* __restrict__ deg, int* __restrict__ incl,
                        int* __restrict__ bsum) {
    __shared__ int sm[256];
    int t = threadIdx.x, i = blockIdx.x * 256 + t;
    int v = (i < NN) ? deg[i] : 0;
    sm[t] = v;
    __syncthreads();
#pragma unroll
    for (int off = 1; off < 256; off <<= 1) {
        int tv = (t >= off) ? sm[t - off] : 0;
        __syncthreads();
        sm[t] += tv;
        __syncthreads();
    }
    if (i < NN) incl[i] = sm[t];
    if (t == 255) bsum[blockIdx.x] = sm[255];
}

__global__ void k_scanB(const int* __restrict__ bsum, int* __restrict__ boff,
                        int* __restrict__ row_ptr) {
    __shared__ int sm[256];
    int t = threadIdx.x;
    int v = (t < NBLK) ? bsum[t] : 0;
    sm[t] = v;
    __syncthreads();
#pragma unroll
    for (int off = 1; off < 256; off <<= 1) {
        int tv = (t >= off) ? sm[t - off] : 0;
        __syncthreads();
        sm[t] += tv;
        __syncthreads();
    }
    if (t < NBLK) boff[t] = sm[t] - v;  // exclusive
    if (t == 255) row_ptr[NN] = sm[255];
}

__global__ void k_scanC(const int* __restrict__ dego, const int* __restrict__ degi,
                        const int* __restrict__ incl, const int* __restrict__ boff,
                        int* __restrict__ row_ptr, int* __restrict__ cursor,
                        float* __restrict__ ns, float* __restrict__ nd) {
    int i = blockIdx.x * 256 + threadIdx.x;
    if (i < NN) {
        int ex = boff[blockIdx.x] + incl[i] - degi[i];
        row_ptr[i] = ex;
        cursor[i] = ex;
        ns[i] = dego[i] > 0 ? rsqrtf((float)dego[i]) : 0.f;
        nd[i] = degi[i] > 0 ? rsqrtf((float)degi[i]) : 0.f;
    }
}

// fill CSR columns; also emit per-edge weight ewt = ns[src]
__global__ void k_fill(const int* __restrict__ src, const int* __restrict__ dst,
                       const float* __restrict__ ns,
                       int* __restrict__ cursor, int* __restrict__ col_src,
                       float* __restrict__ ewt) {
    int e = blockIdx.x * 256 + threadIdx.x;
    if (e < NE) {
        int s = src[e];
        int slot = atomicAdd(&cursor[dst[e]], 1);
        col_src[slot] = s;
        ewt[slot] = ns[s];
    }
}

// ---------------- weight prep ----------------
// 9 QKV mats [256,256] -> merged hi/lo B^T [768][256] per layer; block 0 of each
// matrix also concats its bias into bdst[3][768].
struct QkvPtrs {
    const float* w[9];
    const float* b[9];
    unsigned short* h[3];
    unsigned short* l[3];
    float* bdst;
};

__global__ void k_wsplit9(QkvPtrs P) {
    int m = blockIdx.y;               // 0..8
    int layer = m / 3, which = m - layer * 3;
    int idx = blockIdx.x * 256 + threadIdx.x;   // 0..65535
    int n = idx >> 8, k = idx & 255;
    float w = P.w[m][(size_t)k * 256 + n];
    unsigned short h = f2bf(w);
    size_t o = (size_t)(which * 256 + n) * 256 + k;
    P.h[layer][o] = h;
    P.l[layer][o] = f2bf(w - bf2f(h));
    if (blockIdx.x == 0)
        P.bdst[layer * 768 + which * 256 + (int)threadIdx.x] = P.b[m][threadIdx.x];
}

// Wm [256,256] / W1 [768,512] / W2 [512,256] -> hi/lo B^T, one dispatch.
struct W3Ptrs { const float* w[3]; unsigned short* h[3]; unsigned short* l[3]; };

__global__ void k_wsplit3(W3Ptrs P) {
    int y = blockIdx.y;               // 0..8: 1 unit Wm, 6 units W1, 2 units W2
    int mi, K, N, sub;
    if (y == 0)      { mi = 0; K = 256; N = 256; sub = 0; }
    else if (y < 7)  { mi = 1; K = 768; N = 512; sub = y - 1; }
    else             { mi = 2; K = 512; N = 256; sub = y - 7; }
    int idx = sub * 65536 + blockIdx.x * 256 + (int)threadIdx.x;
    int n = idx / K, k = idx - n * K;
    float w = P.w[mi][(size_t)k * N + n];
    unsigned short h = f2bf(w);
    P.h[mi][idx] = h;
    P.l[mi][idx] = f2bf(w - bf2f(h));
}

// features fp32 -> bf16
__global__ void k_cvt(const float* __restrict__ in, unsigned short* __restrict__ ob, int n4) {
    int i = blockIdx.x * 256 + threadIdx.x;
    if (i < n4) {
        float4 v = ((const float4*)in)[i];
        ushort4 o;
        o.x = f2bf(v.x); o.y = f2bf(v.y); o.z = f2bf(v.z); o.w = f2bf(v.w);
        ((ushort4*)ob)[i] = o;
    }
}

// ---------------- GCN propagate: y[d] = nd[d] * sum ewt[e] * x[src[e]] ----------------
// x bf16 stride ldx; y bf16 [NN,256]. One wave per node; lane owns 4 cols.

__global__ void k_prop(const unsigned short* __restrict__ xb, int ldx,
                       const int* __restrict__ row_ptr, const int* __restrict__ col_src,
                       const float* __restrict__ ewt, const float* __restrict__ ndv,
                       unsigned short* __restrict__ y) {
    int w = (int)((blockIdx.x * 256 + threadIdx.x) >> 6);
    if (w >= NN) return;
    int lane = threadIdx.x & 63;
    int c = lane * 4;
    float a0 = 0, a1 = 0, a2 = 0, a3 = 0;
    int e0 = row_ptr[w], e1 = row_ptr[w + 1];
    int sv = (e0 < e1) ? col_src[e0] : 0;
    for (int p = e0; p < e1; ++p) {
        int sn = (p + 1 < e1) ? col_src[p + 1] : 0;
        float wv = ewt[p];
        const ushort4 xv = *(const ushort4*)(xb + (size_t)sv * ldx + c);
        a0 += wv * bf2f(xv.x); a1 += wv * bf2f(xv.y);
        a2 += wv * bf2f(xv.z); a3 += wv * bf2f(xv.w);
        sv = sn;
    }
    float sc = ndv[w];
    ushort4 o;
    o.x = f2bf(a0 * sc); o.y = f2bf(a1 * sc); o.z = f2bf(a2 * sc); o.w = f2bf(a3 * sc);
    *(ushort4*)(y + (size_t)w * 256 + c) = o;
}

// ---------------- edge attention ----------------
// QKVb [NN,768] bf16: Q 0-255, K 256-511, V 512-767. One wave per dst node.
// 16-lane group g = head g; lane covers 4 dims. Output bf16 into xo (stride 768).

__global__ void k_attn(const unsigned short* __restrict__ QKVb,
                       const int* __restrict__ row_ptr, const int* __restrict__ col_src,
                       unsigned short* __restrict__ xo) {
    int w = (int)((blockIdx.x * 256 + threadIdx.x) >> 6);
    if (w >= NN) return;
    int lane = threadIdx.x & 63;
    int c = lane * 4;
    const ushort4 qu = *(const ushort4*)(QKVb + (size_t)w * 768 + c);
    float q0 = bf2f(qu.x), q1 = bf2f(qu.y), q2 = bf2f(qu.z), q3 = bf2f(qu.w);
    float v0 = 0, v1 = 0, v2 = 0, v3 = 0, z = 0;
    int e0 = row_ptr[w], e1 = row_ptr[w + 1];
    int sv = (e0 < e1) ? col_src[e0] : 0;
    for (int p = e0; p < e1; ++p) {
        int sn = (p + 1 < e1) ? col_src[p + 1] : 0;
        const ushort4 ku = *(const ushort4*)(QKVb + (size_t)sv * 768 + 256 + c);
        const ushort4 vu = *(const ushort4*)(QKVb + (size_t)sv * 768 + 512 + c);
        float t = q0 * bf2f(ku.x) + q1 * bf2f(ku.y) + q2 * bf2f(ku.z) + q3 * bf2f(ku.w);
        t += __shfl_xor(t, 1);
        t += __shfl_xor(t, 2);
        t += __shfl_xor(t, 4);
        t += __shfl_xor(t, 8);
        float scv = __expf(fminf(fmaxf(t * 0.125f, -10.f), 10.f));
        v0 += scv * bf2f(vu.x); v1 += scv * bf2f(vu.y);
        v2 += scv * bf2f(vu.z); v3 += scv * bf2f(vu.w);
        z += scv;
        sv = sn;
    }
    float inv = 1.f / (z + 1e-6f);
    ushort4 o;
    o.x = f2bf(v0 * inv); o.y = f2bf(v1 * inv);
    o.z = f2bf(v2 * inv); o.w = f2bf(v3 * inv);
    *(ushort4*)(xo + (size_t)w * 768 + c) = o;
}

// ---------------- bf16-A 2-term GEMM: C = bf16(relu(A @ W + b)) ----------------
// A bf16 [M,K]; B = W^T split hi/lo bf16 [N,K]. acc = A*W_hi + A*W_lo.
// 128x128 tile per block, one col-tile per block (no A re-fetch loop).
// XCD-chunked swizzle: all NC col-tiles of a row-panel land on the same XCD
// consecutively -> A panel is HBM-fetched once, L2-hit NC-1 times.
// 2-phase double-buffered LDS pipeline, one barrier per K-step.
// LDS stride 36 shorts (18 words): 16 rows hit 16 distinct banks -> conflict-free.

template <int NC>
__global__ __launch_bounds__(256) void k_gemm(
    const unsigned short* __restrict__ A, int lda,
    const unsigned short* __restrict__ Bhi, const unsigned short* __restrict__ Blo,
    const float* __restrict__ bias,
    unsigned short* __restrict__ C, int ldc, int M, int K) {
    const int P = (M + 127) >> 7;            // row panels
    const int xcd = blockIdx.x & 7;
    const int j = blockIdx.x >> 3;
    const int ck = (P >> 3) + ((xcd < (P & 7)) ? 1 : 0);  // panels on this xcd
    if (j >= NC * ck) return;
    const int brow = ((j / NC) * 8 + xcd) * 128;
    const int bcol = (j % NC) * 128;

    __shared__ unsigned short sA[2][128][36];
    __shared__ unsigned short sB[2][2][128][36];
    const int tid = threadIdx.x;
    const int lane = tid & 63;
    const int wid = tid >> 6;
    const int wm = wid & 1, wn = wid >> 1;
    const int fr = lane & 15, kg = lane >> 4;

    const int r0 = tid >> 2, ks0 = (tid & 3) * 8;          // rep 0 staging coords
    const int r1 = (tid + 256) >> 2, ks1 = ((tid + 256) & 3) * 8;
    const int gr0 = brow + r0, gr1 = brow + r1;
    const size_t bb0 = (size_t)(bcol + r0) * K + ks0;
    const size_t bb1 = (size_t)(bcol + r1) * K + ks1;

    f32x4 acc[4][4] = {};
    const int T = K >> 5;

    uint4 av0, av1, vh0, vh1, vl0, vl1;

#define GLOAD(k0)                                                              \
    av0 = make_uint4(0, 0, 0, 0); av1 = make_uint4(0, 0, 0, 0);                \
    if (gr0 < M) av0 = *(const uint4*)(A + (size_t)gr0 * lda + (k0) + ks0);    \
    if (gr1 < M) av1 = *(const uint4*)(A + (size_t)gr1 * lda + (k0) + ks1);    \
    vh0 = *(const uint4*)(Bhi + bb0 + (k0));                                   \
    vh1 = *(const uint4*)(Bhi + bb1 + (k0));                                   \
    vl0 = *(const uint4*)(Blo + bb0 + (k0));                                   \
    vl1 = *(const uint4*)(Blo + bb1 + (k0));

#define LWRITE(buf)                                                            \
    *(uint4*)&sA[buf][r0][ks0] = av0;  *(uint4*)&sA[buf][r1][ks1] = av1;       \
    *(uint4*)&sB[buf][0][r0][ks0] = vh0; *(uint4*)&sB[buf][0][r1][ks1] = vh1;  \
    *(uint4*)&sB[buf][1][r0][ks0] = vl0; *(uint4*)&sB[buf][1][r1][ks1] = vl1;

    GLOAD(0)
    LWRITE(0)
    for (int t = 0; t < T; ++t) {
        __syncthreads();                       // buf[t&1] writes visible
        if (t + 1 < T) { GLOAD((t + 1) << 5) } // issue next chunk early
        const int cur = t & 1;
        s16x8 a[4], bh[4], bl[4];
#pragma unroll
        for (int f = 0; f < 4; ++f) {
            a[f]  = *(const s16x8*)&sA[cur][wm * 64 + f * 16 + fr][kg * 8];
            bh[f] = *(const s16x8*)&sB[cur][0][wn * 64 + f * 16 + fr][kg * 8];
            bl[f] = *(const s16x8*)&sB[cur][1][wn * 64 + f * 16 + fr][kg * 8];
        }
#pragma unroll
        for (int i = 0; i < 4; ++i)
#pragma unroll
            for (int jj = 0; jj < 4; ++jj) {
                acc[i][jj] = __builtin_amdgcn_mfma_f32_16x16x32_bf16(a[i], bh[jj], acc[i][jj], 0, 0, 0);
                acc[i][jj] = __builtin_amdgcn_mfma_f32_16x16x32_bf16(a[i], bl[jj], acc[i][jj], 0, 0, 0);
            }
        if (t + 1 < T) { LWRITE((t + 1) & 1) } // write next buf (loads drained)
    }
#undef GLOAD
#undef LWRITE

#pragma unroll
    for (int i = 0; i < 4; ++i) {
#pragma unroll
        for (int jj = 0; jj < 4; ++jj) {
            int colG = bcol + wn * 64 + jj * 16 + fr;
            float bb = bias[colG];
#pragma unroll
            for (int r = 0; r < 4; ++r) {
                int row = brow + wm * 64 + i * 16 + kg * 4 + r;
                if (row < M) {
                    float v = fmaxf(acc[i][jj][r] + bb, 0.f);
                    C[(size_t)row * ldc + colG] = f2bf(v);
                }
            }
        }
    }
}

// ---------------- final row-dot + sigmoid ----------------

__global__ void k_final(const unsigned short* __restrict__ h2, const float* __restrict__ W3,
                        const float* __restrict__ b3, float* __restrict__ out) {
    int w = (int)((blockIdx.x * 256 + threadIdx.x) >> 6);
    if (w >= NN) return;
    int lane = threadIdx.x & 63;
    ushort4 hu = *(const ushort4*)(h2 + (size_t)w * 256 + lane * 4);
    float4 ww = *(const float4*)(W3 + lane * 4);
    float p = bf2f(hu.x) * ww.x + bf2f(hu.y) * ww.y + bf2f(hu.z) * ww.z + bf2f(hu.w) * ww.w;
    p += __shfl_xor(p, 1);
    p += __shfl_xor(p, 2);
    p += __shfl_xor(p, 4);
    p += __shfl_xor(p, 8);
    p += __shfl_xor(p, 16);
    p += __shfl_xor(p, 32);
    if (lane == 0) out[w] = 1.f / (1.f + __expf(-(p + b3[0])));
}

// sentinel: written iff ws_size too small (diagnosable absmax ~= 0.5, no crash)
__global__ void k_sent(float* __restrict__ out) {
    int i = blockIdx.x * 256 + threadIdx.x;
    if (i < NN) out[i] = 0.5f;
}

// ---------------- launch ----------------

extern "C" void kernel_launch(void* const* d_in, const int* in_sizes, int n_in,
                              void* d_out, int out_size, void* d_ws, size_t ws_size,
                              hipStream_t stream) {
    const float* features = (const float*)d_in[0];
    const int* src = (const int*)d_in[1];
    const int* dst = (const int*)d_in[2];
    const float* Wm = (const float*)d_in[4];
    const float* bm = (const float*)d_in[5];
    const float* W1 = (const float*)d_in[24];
    const float* b1 = (const float*)d_in[25];
    const float* W2 = (const float*)d_in[26];
    const float* b2 = (const float*)d_in[27];
    const float* W3 = (const float*)d_in[28];
    const float* b3 = (const float*)d_in[29];
    float* out = (float*)d_out;

    char* ws = (char*)d_ws;
    size_t off = 0;
    auto alloc = [&](size_t b) -> void* {
        void* p = ws + off;
        off = (off + b + 255) & ~(size_t)255;
        return p;
    };

    int* deg_o = (int*)alloc(NN * 4);   // deg_o and deg_i adjacent: single memset
    int* deg_i = (int*)alloc(NN * 4);
    int* row_ptr = (int*)alloc((NN + 1) * 4);
    int* cursor = (int*)alloc(NN * 4);
    int* col_src = (int*)alloc((size_t)NE * 4);
    float* ewt = (float*)alloc((size_t)NE * 4);
    float* ns = (float*)alloc(NN * 4);
    float* nd = (float*)alloc(NN * 4);
    int* incl = (int*)alloc(NN * 4);
    int* bsum = (int*)alloc(NBLK * 4);
    int* boff = (int*)alloc(NBLK * 4);

    unsigned short* Wmt_h = (unsigned short*)alloc(256 * 256 * 2);
    unsigned short* Wmt_l = (unsigned short*)alloc(256 * 256 * 2);
    unsigned short *Wqkvt_h[3], *Wqkvt_l[3];
    for (int l = 0; l < 3; ++l) {
        Wqkvt_h[l] = (unsigned short*)alloc(768 * 256 * 2);
        Wqkvt_l[l] = (unsigned short*)alloc(768 * 256 * 2);
    }
    float* bqkv = (float*)alloc(3 * 768 * 4);
    unsigned short* W1t_h = (unsigned short*)alloc(512 * 768 * 2);
    unsigned short* W1t_l = (unsigned short*)alloc(512 * 768 * 2);
    unsigned short* W2t_h = (unsigned short*)alloc(256 * 512 * 2);
    unsigned short* W2t_l = (unsigned short*)alloc(256 * 512 * 2);

    unsigned short* fbuf = (unsigned short*)alloc((size_t)NN * 256 * 2);   // 25.6 MB
    unsigned short* QKVb = (unsigned short*)alloc((size_t)NN * 768 * 2);   // 76.8 MB
    unsigned short* y = (unsigned short*)alloc((size_t)NN * 256 * 2);      // 25.6 MB
    unsigned short* xcat = (unsigned short*)alloc((size_t)NN * 768 * 2);   // 76.8 MB

    unsigned short* x0b = xcat;   // [NN,256] packed; dead before attn1 overwrites xcat
    unsigned short* h1 = QKVb;    // [NN,512]; QKVb dead after attn3
    unsigned short* h2 = y;       // [NN,256]; y dead after layer-3 QKV gemm

    (void)in_sizes; (void)n_in; (void)out_size;

    if (off > ws_size) {
        k_sent<<<(NN + 255) / 256, 256, 0, stream>>>(out);
        return;
    }

    // one memset covers adjacent deg_o + deg_i
    hipMemsetAsync(deg_o, 0, (size_t)((char*)deg_i - (char*)deg_o) + NN * 4, stream);
    k_deg<<<(NE + 255) / 256, 256, 0, stream>>>(src, dst, deg_o, deg_i);
    k_scanA<<<NBLK, 256, 0, stream>>>(deg_i, incl, bsum);
    k_scanB<<<1, 256, 0, stream>>>(bsum, boff, row_ptr);
    k_scanC<<<NBLK, 256, 0, stream>>>(deg_o, deg_i, incl, boff, row_ptr, cursor, ns, nd);
    k_fill<<<(NE + 255) / 256, 256, 0, stream>>>(src, dst, ns, cursor, col_src, ewt);

    QkvPtrs qp;
    for (int l = 0; l < 3; ++l) {
        for (int m = 0; m < 3; ++m) {
            qp.w[l * 3 + m] = (const float*)d_in[6 + l * 6 + m * 2];
            qp.b[l * 3 + m] = (const float*)d_in[7 + l * 6 + m * 2];
        }
        qp.h[l] = Wqkvt_h[l];
        qp.l[l] = Wqkvt_l[l];
    }
    qp.bdst = bqkv;
    k_wsplit9<<<dim3(256, 9), 256, 0, stream>>>(qp);

    W3Ptrs wp;
    wp.w[0] = Wm; wp.h[0] = Wmt_h; wp.l[0] = Wmt_l;
    wp.w[1] = W1; wp.h[1] = W1t_h; wp.l[1] = W1t_l;
    wp.w[2] = W2; wp.h[2] = W2t_h; wp.l[2] = W2t_l;
    k_wsplit3<<<dim3(256, 9), 256, 0, stream>>>(wp);

    k_cvt<<<(NN * 64 + 255) / 256, 256, 0, stream>>>(features, fbuf, NN * 64);

    // grid: 8 xcd-slots * NC * ceil(P/8), P = 391 row panels
    const int P8 = ((NN + 127) / 128 + 7) / 8;  // 49

    // x0b = bf16(relu(features @ Wm + bm))
    k_gemm<2><<<8 * 2 * P8, 256, 0, stream>>>(fbuf, 256, Wmt_h, Wmt_l, bm,
                                              x0b, 256, NN, 256);

    const unsigned short* xin = x0b;
    int ldx = 256;
    for (int l = 0; l < 3; ++l) {
        k_prop<<<12500, 256, 0, stream>>>(xin, ldx, row_ptr, col_src, ewt, nd, y);
        k_gemm<6><<<8 * 6 * P8, 256, 0, stream>>>(y, 256, Wqkvt_h[l], Wqkvt_l[l],
                                                  bqkv + l * 768, QKVb, 768, NN, 256);
        k_attn<<<12500, 256, 0, stream>>>(QKVb, row_ptr, col_src, xcat + 256 * l);
        xin = xcat + 256 * l;
        ldx = 768;
    }

    // MLP head
    k_gemm<4><<<8 * 4 * P8, 256, 0, stream>>>(xcat, 768, W1t_h, W1t_l, b1,
                                              h1, 512, NN, 768);
    k_gemm<2><<<8 * 2 * P8, 256, 0, stream>>>(h1, 512, W2t_h, W2t_l, b2,
                                              h2, 256, NN, 512);
    k_final<<<12500, 256, 0, stream>>>(h2, W3, b3, out);
}

// Round 8
// 1179.144 us; speedup vs baseline: 1.1517x; 1.0536x over previous
//
#include <hip/hip_runtime.h>
#include <stdint.h>

#define NN 50000
#define NE 800000
#define NBLK 196   // ceil(NN/256)

typedef float f32x4 __attribute__((ext_vector_type(4)));
typedef short s16x8 __attribute__((ext_vector_type(8)));

__device__ __forceinline__ float bf2f(unsigned short u) {
    union { unsigned int i; float f; } v; v.i = ((unsigned int)u) << 16; return v.f;
}
__device__ __forceinline__ unsigned short f2bf(float x) {
    union { float f; unsigned int i; } v; v.f = x;
    unsigned int r = v.i + 0x7FFFu + ((v.i >> 16) & 1u);
    return (unsigned short)(r >> 16);
}

// ---------------- graph preprocessing ----------------

__global__ void k_deg(const int* __restrict__ src, const int* __restrict__ dst,
                      int* __restrict__ dego, int* __restrict__ degi) {
    int e = blockIdx.x * 256 + threadIdx.x;
    if (e < NE) {
        atomicAdd(&dego[src[e]], 1);
        atomicAdd(&degi[dst[e]], 1);
    }
}

// parallel exclusive scan of deg_i (3 phases); scanC also computes norms
__global__ void k_scanA(const int* __restrict__ deg, int* __restrict__ incl,
                        int* __restrict__ bsum) {
    __shared__ int sm[256];
    int t = threadIdx.x, i = blockIdx.x * 256 + t;
    int v = (i < NN) ? deg[i] : 0;
    sm[t] = v;
    __syncthreads();
#pragma unroll
    for (int off = 1; off < 256; off <<= 1) {
        int tv = (t >= off) ? sm[t - off] : 0;
        __syncthreads();
        sm[t] += tv;
        __syncthreads();
    }
    if (i < NN) incl[i] = sm[t];
    if (t == 255) bsum[blockIdx.x] = sm[255];
}

__global__ void k_scanB(const int* __restrict__ bsum, int* __restrict__ boff,
                        int* __restrict__ row_ptr) {
    __shared__ int sm[256];
    int t = threadIdx.x;
    int v = (t < NBLK) ? bsum[t] : 0;
    sm[t] = v;
    __syncthreads();
#pragma unroll
    for (int off = 1; off < 256; off <<= 1) {
        int tv = (t >= off) ? sm[t - off] : 0;
        __syncthreads();
        sm[t] += tv;
        __syncthreads();
    }
    if (t < NBLK) boff[t] = sm[t] - v;  // exclusive
    if (t == 255) row_ptr[NN] = sm[255];
}

__global__ void k_scanC(const int* __restrict__ dego, const int* __restrict__ degi,
                        const int* __restrict__ incl, const int* __restrict__ boff,
                        int* __restrict__ row_ptr, int* __restrict__ cursor,
                        float* __restrict__ ns, float* __restrict__ nd) {
    int i = blockIdx.x * 256 + threadIdx.x;
    if (i < NN) {
        int ex = boff[blockIdx.x] + incl[i] - degi[i];
        row_ptr[i] = ex;
        cursor[i] = ex;
        ns[i] = dego[i] > 0 ? rsqrtf((float)dego[i]) : 0.f;
        nd[i] = degi[i] > 0 ? rsqrtf((float)degi[i]) : 0.f;
    }
}

// fill CSR columns; also emit per-edge weight ewt = ns[src]
__global__ void k_fill(const int* __restrict__ src, const int* __restrict__ dst,
                       const float* __restrict__ ns,
                       int* __restrict__ cursor, int* __restrict__ col_src,
                       float* __restrict__ ewt) {
    int e = blockIdx.x * 256 + threadIdx.x;
    if (e < NE) {
        int s = src[e];
        int slot = atomicAdd(&cursor[dst[e]], 1);
        col_src[slot] = s;
        ewt[slot] = ns[s];
    }
}

// ---------------- weight prep ----------------
struct QkvPtrs {
    const float* w[9];
    const float* b[9];
    unsigned short* h[3];
    unsigned short* l[3];
    float* bdst;
};

__global__ void k_wsplit9(QkvPtrs P) {
    int m = blockIdx.y;               // 0..8
    int layer = m / 3, which = m - layer * 3;
    int idx = blockIdx.x * 256 + threadIdx.x;   // 0..65535
    int n = idx >> 8, k = idx & 255;
    float w = P.w[m][(size_t)k * 256 + n];
    unsigned short h = f2bf(w);
    size_t o = (size_t)(which * 256 + n) * 256 + k;
    P.h[layer][o] = h;
    P.l[layer][o] = f2bf(w - bf2f(h));
    if (blockIdx.x == 0)
        P.bdst[layer * 768 + which * 256 + (int)threadIdx.x] = P.b[m][threadIdx.x];
}

// Wm [256,256] / W1 [768,512] / W2 [512,256] -> hi/lo B^T, one dispatch.
struct W3Ptrs { const float* w[3]; unsigned short* h[3]; unsigned short* l[3]; };

__global__ void k_wsplit3(W3Ptrs P) {
    int y = blockIdx.y;               // 0..8: 1 unit Wm, 6 units W1, 2 units W2
    int mi, K, N, sub;
    if (y == 0)      { mi = 0; K = 256; N = 256; sub = 0; }
    else if (y < 7)  { mi = 1; K = 768; N = 512; sub = y - 1; }
    else             { mi = 2; K = 512; N = 256; sub = y - 7; }
    int idx = sub * 65536 + blockIdx.x * 256 + (int)threadIdx.x;
    int n = idx / K, k = idx - n * K;
    float w = P.w[mi][(size_t)k * N + n];
    unsigned short h = f2bf(w);
    P.h[mi][idx] = h;
    P.l[mi][idx] = f2bf(w - bf2f(h));
}

// features fp32 -> bf16
__global__ void k_cvt(const float* __restrict__ in, unsigned short* __restrict__ ob, int n4) {
    int i = blockIdx.x * 256 + threadIdx.x;
    if (i < n4) {
        float4 v = ((const float4*)in)[i];
        ushort4 o;
        o.x = f2bf(v.x); o.y = f2bf(v.y); o.z = f2bf(v.z); o.w = f2bf(v.w);
        ((ushort4*)ob)[i] = o;
    }
}

// ---------------- GCN propagate: y[d] = nd[d] * sum ewt[e] * x[src[e]] ----------------
// x bf16 stride ldx; y bf16 [NN,256]. One wave per node; 2-edge unroll.

__global__ void k_prop(const unsigned short* __restrict__ xb, int ldx,
                       const int* __restrict__ row_ptr, const int* __restrict__ col_src,
                       const float* __restrict__ ewt, const float* __restrict__ ndv,
                       unsigned short* __restrict__ y) {
    int w = (int)((blockIdx.x * 256 + threadIdx.x) >> 6);
    if (w >= NN) return;
    int lane = threadIdx.x & 63;
    int c = lane * 4;
    float a0 = 0, a1 = 0, a2 = 0, a3 = 0;
    int e0 = row_ptr[w], e1 = row_ptr[w + 1];
    int p = e0;
    for (; p + 2 <= e1; p += 2) {
        int s0 = col_src[p], s1 = col_src[p + 1];
        float w0 = ewt[p], w1 = ewt[p + 1];
        const ushort4 x0 = *(const ushort4*)(xb + (size_t)s0 * ldx + c);
        const ushort4 x1 = *(const ushort4*)(xb + (size_t)s1 * ldx + c);
        a0 += w0 * bf2f(x0.x) + w1 * bf2f(x1.x);
        a1 += w0 * bf2f(x0.y) + w1 * bf2f(x1.y);
        a2 += w0 * bf2f(x0.z) + w1 * bf2f(x1.z);
        a3 += w0 * bf2f(x0.w) + w1 * bf2f(x1.w);
    }
    if (p < e1) {
        int s0 = col_src[p];
        float w0 = ewt[p];
        const ushort4 x0 = *(const ushort4*)(xb + (size_t)s0 * ldx + c);
        a0 += w0 * bf2f(x0.x); a1 += w0 * bf2f(x0.y);
        a2 += w0 * bf2f(x0.z); a3 += w0 * bf2f(x0.w);
    }
    float sc = ndv[w];
    ushort4 o;
    o.x = f2bf(a0 * sc); o.y = f2bf(a1 * sc); o.z = f2bf(a2 * sc); o.w = f2bf(a3 * sc);
    *(ushort4*)(y + (size_t)w * 256 + c) = o;
}

// ---------------- edge attention ----------------
// QKVb [NN,768] bf16: Q 0-255, K 256-511, V 512-767. One wave per dst node.
// 16-lane group g = head g; lane covers 4 dims. 2-edge unroll.

__global__ void k_attn(const unsigned short* __restrict__ QKVb,
                       const int* __restrict__ row_ptr, const int* __restrict__ col_src,
                       unsigned short* __restrict__ xo) {
    int w = (int)((blockIdx.x * 256 + threadIdx.x) >> 6);
    if (w >= NN) return;
    int lane = threadIdx.x & 63;
    int c = lane * 4;
    const ushort4 qu = *(const ushort4*)(QKVb + (size_t)w * 768 + c);
    float q0 = bf2f(qu.x), q1 = bf2f(qu.y), q2 = bf2f(qu.z), q3 = bf2f(qu.w);
    float v0 = 0, v1 = 0, v2 = 0, v3 = 0, z = 0;
    int e0 = row_ptr[w], e1 = row_ptr[w + 1];
    int p = e0;
    for (; p + 2 <= e1; p += 2) {
        int s0 = col_src[p], s1 = col_src[p + 1];
        const ushort4 k0 = *(const ushort4*)(QKVb + (size_t)s0 * 768 + 256 + c);
        const ushort4 u0 = *(const ushort4*)(QKVb + (size_t)s0 * 768 + 512 + c);
        const ushort4 k1 = *(const ushort4*)(QKVb + (size_t)s1 * 768 + 256 + c);
        const ushort4 u1 = *(const ushort4*)(QKVb + (size_t)s1 * 768 + 512 + c);
        float t0 = q0 * bf2f(k0.x) + q1 * bf2f(k0.y) + q2 * bf2f(k0.z) + q3 * bf2f(k0.w);
        float t1 = q0 * bf2f(k1.x) + q1 * bf2f(k1.y) + q2 * bf2f(k1.z) + q3 * bf2f(k1.w);
        t0 += __shfl_xor(t0, 1); t1 += __shfl_xor(t1, 1);
        t0 += __shfl_xor(t0, 2); t1 += __shfl_xor(t1, 2);
        t0 += __shfl_xor(t0, 4); t1 += __shfl_xor(t1, 4);
        t0 += __shfl_xor(t0, 8); t1 += __shfl_xor(t1, 8);
        float sc0 = __expf(fminf(fmaxf(t0 * 0.125f, -10.f), 10.f));
        float sc1 = __expf(fminf(fmaxf(t1 * 0.125f, -10.f), 10.f));
        v0 += sc0 * bf2f(u0.x) + sc1 * bf2f(u1.x);
        v1 += sc0 * bf2f(u0.y) + sc1 * bf2f(u1.y);
        v2 += sc0 * bf2f(u0.z) + sc1 * bf2f(u1.z);
        v3 += sc0 * bf2f(u0.w) + sc1 * bf2f(u1.w);
        z += sc0 + sc1;
    }
    if (p < e1) {
        int s0 = col_src[p];
        const ushort4 k0 = *(const ushort4*)(QKVb + (size_t)s0 * 768 + 256 + c);
        const ushort4 u0 = *(const ushort4*)(QKVb + (size_t)s0 * 768 + 512 + c);
        float t0 = q0 * bf2f(k0.x) + q1 * bf2f(k0.y) + q2 * bf2f(k0.z) + q3 * bf2f(k0.w);
        t0 += __shfl_xor(t0, 1);
        t0 += __shfl_xor(t0, 2);
        t0 += __shfl_xor(t0, 4);
        t0 += __shfl_xor(t0, 8);
        float sc0 = __expf(fminf(fmaxf(t0 * 0.125f, -10.f), 10.f));
        v0 += sc0 * bf2f(u0.x); v1 += sc0 * bf2f(u0.y);
        v2 += sc0 * bf2f(u0.z); v3 += sc0 * bf2f(u0.w);
        z += sc0;
    }
    float inv = 1.f / (z + 1e-6f);
    ushort4 o;
    o.x = f2bf(v0 * inv); o.y = f2bf(v1 * inv);
    o.z = f2bf(v2 * inv); o.w = f2bf(v3 * inv);
    *(ushort4*)(xo + (size_t)w * 768 + c) = o;
}

// ---------------- bf16-A 2-term GEMM: C = bf16(relu(A @ W + b)) ----------------
// Fragment-order LDS layout: granule L(r,kb) = (r>>4)*64 + kb*16 + (r&15),
// addr = L*16B. MFMA ds_read_b128 for fragment f = base(f) + lane*16B (linear,
// 0 bank conflicts). Staging thread tid writes granule L=tid (+256 for rep 1) —
// also lane-linear, 0 conflicts. Global load row = (L>>6)*16 + (L&15),
// k-off = ((L>>4)&3)*8: same 16-rows x 64B coalescing as row-major staging.
// LDS 48KB (no padding) -> 3 blocks/CU. XCD-chunked swizzle keeps all NC
// col-tiles of a row panel on one XCD (A HBM-fetched once).

template <int NC>
__global__ __launch_bounds__(256) void k_gemm(
    const unsigned short* __restrict__ A, int lda,
    const unsigned short* __restrict__ Bhi, const unsigned short* __restrict__ Blo,
    const float* __restrict__ bias,
    unsigned short* __restrict__ C, int ldc, int M, int K) {
    const int P = (M + 127) >> 7;            // row panels
    const int xcd = blockIdx.x & 7;
    const int j = blockIdx.x >> 3;
    const int ck = (P >> 3) + ((xcd < (P & 7)) ? 1 : 0);  // panels on this xcd
    if (j >= NC * ck) return;
    const int brow = ((j / NC) * 8 + xcd) * 128;
    const int bcol = (j % NC) * 128;

    __shared__ unsigned short smem[24576];   // 48KB
#define SA(b)  (smem + (b) * 4096)
#define SBH(b) (smem + 8192 + (b) * 4096)
#define SBL(b) (smem + 16384 + (b) * 4096)

    const int tid = threadIdx.x;
    const int lane = tid & 63;
    const int wid = tid >> 6;
    const int wm = wid & 1, wn = wid >> 1;
    const int fr = lane & 15, kg = lane >> 4;

    // staging coords from granule ids L0=tid, L1=tid+256
    const int r0 = ((tid >> 6) << 4) | (tid & 15);        // 0..63
    const int r1 = r0 + 64;                               // 64..127
    const int ko0 = ((tid >> 4) & 3) * 8;
    const int gr0 = brow + r0, gr1 = brow + r1;
    const size_t aoff0 = (size_t)gr0 * lda + ko0;
    const size_t aoff1 = (size_t)gr1 * lda + ko0;
    const size_t boff0 = (size_t)(bcol + r0) * K + ko0;
    const size_t boff1 = (size_t)(bcol + r1) * K + ko0;

    f32x4 acc[4][4] = {};
    const int T = K >> 5;

    uint4 av0, av1, vh0, vh1, vl0, vl1;

#define GLOAD(k0)                                                              \
    av0 = make_uint4(0, 0, 0, 0); av1 = make_uint4(0, 0, 0, 0);                \
    if (gr0 < M) av0 = *(const uint4*)(A + aoff0 + (k0));                      \
    if (gr1 < M) av1 = *(const uint4*)(A + aoff1 + (k0));                      \
    vh0 = *(const uint4*)(Bhi + boff0 + (k0));                                 \
    vh1 = *(const uint4*)(Bhi + boff1 + (k0));                                 \
    vl0 = *(const uint4*)(Blo + boff0 + (k0));                                 \
    vl1 = *(const uint4*)(Blo + boff1 + (k0));

#define LWRITE(b)                                                              \
    *(uint4*)(SA(b) + tid * 8) = av0;  *(uint4*)(SA(b) + 2048 + tid * 8) = av1;\
    *(uint4*)(SBH(b) + tid * 8) = vh0; *(uint4*)(SBH(b) + 2048 + tid * 8) = vh1;\
    *(uint4*)(SBL(b) + tid * 8) = vl0; *(uint4*)(SBL(b) + 2048 + tid * 8) = vl1;

    GLOAD(0)
    LWRITE(0)
    for (int t = 0; t < T; ++t) {
        __syncthreads();                       // buf[t&1] writes visible
        if (t + 1 < T) { GLOAD((t + 1) << 5) } // issue next chunk early
        const int cur = t & 1;
        s16x8 a[4], bh[4], bl[4];
#pragma unroll
        for (int f = 0; f < 4; ++f) {
            a[f]  = *(const s16x8*)(SA(cur) + (wm * 4 + f) * 512 + lane * 8);
            bh[f] = *(const s16x8*)(SBH(cur) + (wn * 4 + f) * 512 + lane * 8);
            bl[f] = *(const s16x8*)(SBL(cur) + (wn * 4 + f) * 512 + lane * 8);
        }
#pragma unroll
        for (int i = 0; i < 4; ++i)
#pragma unroll
            for (int jj = 0; jj < 4; ++jj) {
                acc[i][jj] = __builtin_amdgcn_mfma_f32_16x16x32_bf16(a[i], bh[jj], acc[i][jj], 0, 0, 0);
                acc[i][jj] = __builtin_amdgcn_mfma_f32_16x16x32_bf16(a[i], bl[jj], acc[i][jj], 0, 0, 0);
            }
        if (t + 1 < T) { LWRITE((t + 1) & 1) } // write next buf (loads drained)
    }
#undef GLOAD
#undef LWRITE
#undef SA
#undef SBH
#undef SBL

#pragma unroll
    for (int i = 0; i < 4; ++i) {
#pragma unroll
        for (int jj = 0; jj < 4; ++jj) {
            int colG = bcol + wn * 64 + jj * 16 + fr;
            float bb = bias[colG];
#pragma unroll
            for (int r = 0; r < 4; ++r) {
                int row = brow + wm * 64 + i * 16 + kg * 4 + r;
                if (row < M) {
                    float v = fmaxf(acc[i][jj][r] + bb, 0.f);
                    C[(size_t)row * ldc + colG] = f2bf(v);
                }
            }
        }
    }
}

// ---------------- final row-dot + sigmoid ----------------

__global__ void k_final(const unsigned short* __restrict__ h2, const float* __restrict__ W3,
                        const float* __restrict__ b3, float* __restrict__ out) {
    int w = (int)((blockIdx.x * 256 + threadIdx.x) >> 6);
    if (w >= NN) return;
    int lane = threadIdx.x & 63;
    ushort4 hu = *(const ushort4*)(h2 + (size_t)w * 256 + lane * 4);
    float4 ww = *(const float4*)(W3 + lane * 4);
    float p = bf2f(hu.x) * ww.x + bf2f(hu.y) * ww.y + bf2f(hu.z) * ww.z + bf2f(hu.w) * ww.w;
    p += __shfl_xor(p, 1);
    p += __shfl_xor(p, 2);
    p += __shfl_xor(p, 4);
    p += __shfl_xor(p, 8);
    p += __shfl_xor(p, 16);
    p += __shfl_xor(p, 32);
    if (lane == 0) out[w] = 1.f / (1.f + __expf(-(p + b3[0])));
}

// sentinel: written iff ws_size too small (diagnosable absmax ~= 0.5, no crash)
__global__ void k_sent(float* __restrict__ out) {
    int i = blockIdx.x * 256 + threadIdx.x;
    if (i < NN) out[i] = 0.5f;
}

// ---------------- launch ----------------

extern "C" void kernel_launch(void* const* d_in, const int* in_sizes, int n_in,
                              void* d_out, int out_size, void* d_ws, size_t ws_size,
                              hipStream_t stream) {
    const float* features = (const float*)d_in[0];
    const int* src = (const int*)d_in[1];
    const int* dst = (const int*)d_in[2];
    const float* Wm = (const float*)d_in[4];
    const float* bm = (const float*)d_in[5];
    const float* W1 = (const float*)d_in[24];
    const float* b1 = (const float*)d_in[25];
    const float* W2 = (const float*)d_in[26];
    const float* b2 = (const float*)d_in[27];
    const float* W3 = (const float*)d_in[28];
    const float* b3 = (const float*)d_in[29];
    float* out = (float*)d_out;

    char* ws = (char*)d_ws;
    size_t off = 0;
    auto alloc = [&](size_t b) -> void* {
        void* p = ws + off;
        off = (off + b + 255) & ~(size_t)255;
        return p;
    };

    int* deg_o = (int*)alloc(NN * 4);   // deg_o and deg_i adjacent: single memset
    int* deg_i = (int*)alloc(NN * 4);
    int* row_ptr = (int*)alloc((NN + 1) * 4);
    int* cursor = (int*)alloc(NN * 4);
    int* col_src = (int*)alloc((size_t)NE * 4);
    float* ewt = (float*)alloc((size_t)NE * 4);
    float* ns = (float*)alloc(NN * 4);
    float* nd = (float*)alloc(NN * 4);
    int* incl = (int*)alloc(NN * 4);
    int* bsum = (int*)alloc(NBLK * 4);
    int* boff = (int*)alloc(NBLK * 4);

    unsigned short* Wmt_h = (unsigned short*)alloc(256 * 256 * 2);
    unsigned short* Wmt_l = (unsigned short*)alloc(256 * 256 * 2);
    unsigned short *Wqkvt_h[3], *Wqkvt_l[3];
    for (int l = 0; l < 3; ++l) {
        Wqkvt_h[l] = (unsigned short*)alloc(768 * 256 * 2);
        Wqkvt_l[l] = (unsigned short*)alloc(768 * 256 * 2);
    }
    float* bqkv = (float*)alloc(3 * 768 * 4);
    unsigned short* W1t_h = (unsigned short*)alloc(512 * 768 * 2);
    unsigned short* W1t_l = (unsigned short*)alloc(512 * 768 * 2);
    unsigned short* W2t_h = (unsigned short*)alloc(256 * 512 * 2);
    unsigned short* W2t_l = (unsigned short*)alloc(256 * 512 * 2);

    unsigned short* fbuf = (unsigned short*)alloc((size_t)NN * 256 * 2);   // 25.6 MB
    unsigned short* QKVb = (unsigned short*)alloc((size_t)NN * 768 * 2);   // 76.8 MB
    unsigned short* y = (unsigned short*)alloc((size_t)NN * 256 * 2);      // 25.6 MB
    unsigned short* xcat = (unsigned short*)alloc((size_t)NN * 768 * 2);   // 76.8 MB

    unsigned short* x0b = xcat;   // [NN,256] packed; dead before attn1 overwrites xcat
    unsigned short* h1 = QKVb;    // [NN,512]; QKVb dead after attn3
    unsigned short* h2 = y;       // [NN,256]; y dead after layer-3 QKV gemm

    (void)in_sizes; (void)n_in; (void)out_size;

    if (off > ws_size) {
        k_sent<<<(NN + 255) / 256, 256, 0, stream>>>(out);
        return;
    }

    // one memset covers adjacent deg_o + deg_i
    hipMemsetAsync(deg_o, 0, (size_t)((char*)deg_i - (char*)deg_o) + NN * 4, stream);
    k_deg<<<(NE + 255) / 256, 256, 0, stream>>>(src, dst, deg_o, deg_i);
    k_scanA<<<NBLK, 256, 0, stream>>>(deg_i, incl, bsum);
    k_scanB<<<1, 256, 0, stream>>>(bsum, boff, row_ptr);
    k_scanC<<<NBLK, 256, 0, stream>>>(deg_o, deg_i, incl, boff, row_ptr, cursor, ns, nd);
    k_fill<<<(NE + 255) / 256, 256, 0, stream>>>(src, dst, ns, cursor, col_src, ewt);

    QkvPtrs qp;
    for (int l = 0; l < 3; ++l) {
        for (int m = 0; m < 3; ++m) {
            qp.w[l * 3 + m] = (const float*)d_in[6 + l * 6 + m * 2];
            qp.b[l * 3 + m] = (const float*)d_in[7 + l * 6 + m * 2];
        }
        qp.h[l] = Wqkvt_h[l];
        qp.l[l] = Wqkvt_l[l];
    }
    qp.bdst = bqkv;
    k_wsplit9<<<dim3(256, 9), 256, 0, stream>>>(qp);

    W3Ptrs wp;
    wp.w[0] = Wm; wp.h[0] = Wmt_h; wp.l[0] = Wmt_l;
    wp.w[1] = W1; wp.h[1] = W1t_h; wp.l[1] = W1t_l;
    wp.w[2] = W2; wp.h[2] = W2t_h; wp.l[2] = W2t_l;
    k_wsplit3<<<dim3(256, 9), 256, 0, stream>>>(wp);

    k_cvt<<<(NN * 64 + 255) / 256, 256, 0, stream>>>(features, fbuf, NN * 64);

    // grid: 8 xcd-slots * NC * ceil(P/8), P = 391 row panels
    const int P8 = ((NN + 127) / 128 + 7) / 8;  // 49

    // x0b = bf16(relu(features @ Wm + bm))
    k_gemm<2><<<8 * 2 * P8, 256, 0, stream>>>(fbuf, 256, Wmt_h, Wmt_l, bm,
                                              x0b, 256, NN, 256);

    const unsigned short* xin = x0b;
    int ldx = 256;
    for (int l = 0; l < 3; ++l) {
        k_prop<<<12500, 256, 0, stream>>>(xin, ldx, row_ptr, col_src, ewt, nd, y);
        k_gemm<6><<<8 * 6 * P8, 256, 0, stream>>>(y, 256, Wqkvt_h[l], Wqkvt_l[l],
                                                  bqkv + l * 768, QKVb, 768, NN, 256);
        k_attn<<<12500, 256, 0, stream>>>(QKVb, row_ptr, col_src, xcat + 256 * l);
        xin = xcat + 256 * l;
        ldx = 768;
    }

    // MLP head
    k_gemm<4><<<8 * 4 * P8, 256, 0, stream>>>(xcat, 768, W1t_h, W1t_l, b1,
                                              h1, 512, NN, 768);
    k_gemm<2><<<8 * 2 * P8, 256, 0, stream>>>(h1, 512, W2t_h, W2t_l, b2,
                                              h2, 256, NN, 512);
    k_final<<<12500, 256, 0, stream>>>(h2, W3, b3, out);
}

// Round 9
// 1040.952 us; speedup vs baseline: 1.3046x; 1.1328x over previous
//
#include <hip/hip_runtime.h>
#include <stdint.h>

#define NN 50000
#define NE 800000
#define NBLK 196   // ceil(NN/256)

typedef float f32x4 __attribute__((ext_vector_type(4)));
typedef short s16x8 __attribute__((ext_vector_type(8)));

__device__ __forceinline__ float bf2f(unsigned short u) {
    union { unsigned int i; float f; } v; v.i = ((unsigned int)u) << 16; return v.f;
}
__device__ __forceinline__ unsigned short f2bf(float x) {
    union { float f; unsigned int i; } v; v.f = x;
    unsigned int r = v.i + 0x7FFFu + ((v.i >> 16) & 1u);
    return (unsigned short)(r >> 16);
}

// ---------------- graph preprocessing ----------------

__global__ void k_deg(const int* __restrict__ src, const int* __restrict__ dst,
                      int* __restrict__ dego, int* __restrict__ degi) {
    int e = blockIdx.x * 256 + threadIdx.x;
    if (e < NE) {
        atomicAdd(&dego[src[e]], 1);
        atomicAdd(&degi[dst[e]], 1);
    }
}

__global__ void k_scanA(const int* __restrict__ deg, int* __restrict__ incl,
                        int* __restrict__ bsum) {
    __shared__ int sm[256];
    int t = threadIdx.x, i = blockIdx.x * 256 + t;
    int v = (i < NN) ? deg[i] : 0;
    sm[t] = v;
    __syncthreads();
#pragma unroll
    for (int off = 1; off < 256; off <<= 1) {
        int tv = (t >= off) ? sm[t - off] : 0;
        __syncthreads();
        sm[t] += tv;
        __syncthreads();
    }
    if (i < NN) incl[i] = sm[t];
    if (t == 255) bsum[blockIdx.x] = sm[255];
}

__global__ void k_scanB(const int* __restrict__ bsum, int* __restrict__ boff,
                        int* __restrict__ row_ptr) {
    __shared__ int sm[256];
    int t = threadIdx.x;
    int v = (t < NBLK) ? bsum[t] : 0;
    sm[t] = v;
    __syncthreads();
#pragma unroll
    for (int off = 1; off < 256; off <<= 1) {
        int tv = (t >= off) ? sm[t - off] : 0;
        __syncthreads();
        sm[t] += tv;
        __syncthreads();
    }
    if (t < NBLK) boff[t] = sm[t] - v;  // exclusive
    if (t == 255) row_ptr[NN] = sm[255];
}

__global__ void k_scanC(const int* __restrict__ dego, const int* __restrict__ degi,
                        const int* __restrict__ incl, const int* __restrict__ boff,
                        int* __restrict__ row_ptr, int* __restrict__ cursor,
                        float* __restrict__ ns, float* __restrict__ nd) {
    int i = blockIdx.x * 256 + threadIdx.x;
    if (i < NN) {
        int ex = boff[blockIdx.x] + incl[i] - degi[i];
        row_ptr[i] = ex;
        cursor[i] = ex;
        ns[i] = dego[i] > 0 ? rsqrtf((float)dego[i]) : 0.f;
        nd[i] = degi[i] > 0 ? rsqrtf((float)degi[i]) : 0.f;
    }
}

__global__ void k_fill(const int* __restrict__ src, const int* __restrict__ dst,
                       const float* __restrict__ ns,
                       int* __restrict__ cursor, int* __restrict__ col_src,
                       float* __restrict__ ewt) {
    int e = blockIdx.x * 256 + threadIdx.x;
    if (e < NE) {
        int s = src[e];
        int slot = atomicAdd(&cursor[dst[e]], 1);
        col_src[slot] = s;
        ewt[slot] = ns[s];
    }
}

// ---------------- weight packing: fragment-stream order ----------------
// Packed stream for W^T [N,K]: tile cb (128 cols) x K-step t (32 k) x hl x
// granule g (0..511) x elem e (0..7). Granule g(r,kb) = (r>>4)*64+kb*16+(r&15),
// r = col within tile, k = t*32+kb*8+e. Short index:
//   ((cb*T + t)*1024 + hl*512 + g)*8 + e,  T = K/32.
// GEMM staging then loads 16B per thread at CONSECUTIVE addresses (coalesced)
// and writes LDS linearly (conflict-free).

// generic: W [K,N] fp32 row-major -> packed stream. one thread per granule.
__global__ void k_packw(const float* __restrict__ W, unsigned short* __restrict__ out,
                        int K, int N, int ngran) {
    int gid = blockIdx.x * 256 + threadIdx.x;
    if (gid >= ngran) return;
    int T1024 = (K >> 5) << 10;
    int cb = gid / T1024, rem = gid - cb * T1024;
    int t = rem >> 10, rem2 = rem & 1023;
    int hl = rem2 >> 9, g = rem2 & 511;
    int r = ((g >> 6) << 4) | (g & 15);
    int kb = (g >> 4) & 3;
    int n = cb * 128 + r;
    int k = t * 32 + kb * 8;
    unsigned short vals[8];
#pragma unroll
    for (int e = 0; e < 8; ++e) {
        float w = W[(size_t)(k + e) * N + n];
        unsigned short h = f2bf(w);
        vals[e] = hl ? f2bf(w - bf2f(h)) : h;
    }
    *(ushort4*)(out + (size_t)gid * 8) = make_ushort4(vals[0], vals[1], vals[2], vals[3]);
    *(ushort4*)(out + (size_t)gid * 8 + 4) = make_ushort4(vals[4], vals[5], vals[6], vals[7]);
}

// QKV: 9 mats [256,256] -> per-layer merged stream (N=768, K=256, T=8).
struct QkvPtrs { const float* w[9]; unsigned short* out; };

__global__ void k_packqkv(QkvPtrs P) {
    int layer = blockIdx.y;
    int gid = blockIdx.x * 256 + threadIdx.x;       // 0..49151
    int cb = gid >> 13, rem = gid & 8191;           // T*1024 = 8192
    int t = rem >> 10, rem2 = rem & 1023;
    int hl = rem2 >> 9, g = rem2 & 511;
    int r = ((g >> 6) << 4) | (g & 15);
    int kb = (g >> 4) & 3;
    int n = cb * 128 + r;
    int which = n >> 8, nl = n & 255;
    int k = t * 32 + kb * 8;
    const float* W = P.w[layer * 3 + which];
    unsigned short vals[8];
#pragma unroll
    for (int e = 0; e < 8; ++e) {
        float w = W[(size_t)(k + e) * 256 + nl];
        unsigned short h = f2bf(w);
        vals[e] = hl ? f2bf(w - bf2f(h)) : h;
    }
    size_t o = ((size_t)layer * 49152 + gid) * 8;
    *(ushort4*)(P.out + o) = make_ushort4(vals[0], vals[1], vals[2], vals[3]);
    *(ushort4*)(P.out + o + 4) = make_ushort4(vals[4], vals[5], vals[6], vals[7]);
}

struct BiasPtrs { const float* b[9]; float* dst; };

__global__ void k_bcat(BiasPtrs P) {
    int m = blockIdx.x;
    int layer = m / 3, which = m - layer * 3;
    P.dst[layer * 768 + which * 256 + (int)threadIdx.x] = P.b[m][threadIdx.x];
}

// features fp32 -> bf16
__global__ void k_cvt(const float* __restrict__ in, unsigned short* __restrict__ ob, int n4) {
    int i = blockIdx.x * 256 + threadIdx.x;
    if (i < n4) {
        float4 v = ((const float4*)in)[i];
        ushort4 o;
        o.x = f2bf(v.x); o.y = f2bf(v.y); o.z = f2bf(v.z); o.w = f2bf(v.w);
        ((ushort4*)ob)[i] = o;
    }
}

// ---------------- GCN propagate ----------------

__global__ void k_prop(const unsigned short* __restrict__ xb, int ldx,
                       const int* __restrict__ row_ptr, const int* __restrict__ col_src,
                       const float* __restrict__ ewt, const float* __restrict__ ndv,
                       unsigned short* __restrict__ y) {
    int w = (int)((blockIdx.x * 256 + threadIdx.x) >> 6);
    if (w >= NN) return;
    int lane = threadIdx.x & 63;
    int c = lane * 4;
    float a0 = 0, a1 = 0, a2 = 0, a3 = 0;
    int e0 = row_ptr[w], e1 = row_ptr[w + 1];
    int p = e0;
    for (; p + 2 <= e1; p += 2) {
        int s0 = col_src[p], s1 = col_src[p + 1];
        float w0 = ewt[p], w1 = ewt[p + 1];
        const ushort4 x0 = *(const ushort4*)(xb + (size_t)s0 * ldx + c);
        const ushort4 x1 = *(const ushort4*)(xb + (size_t)s1 * ldx + c);
        a0 += w0 * bf2f(x0.x) + w1 * bf2f(x1.x);
        a1 += w0 * bf2f(x0.y) + w1 * bf2f(x1.y);
        a2 += w0 * bf2f(x0.z) + w1 * bf2f(x1.z);
        a3 += w0 * bf2f(x0.w) + w1 * bf2f(x1.w);
    }
    if (p < e1) {
        int s0 = col_src[p];
        float w0 = ewt[p];
        const ushort4 x0 = *(const ushort4*)(xb + (size_t)s0 * ldx + c);
        a0 += w0 * bf2f(x0.x); a1 += w0 * bf2f(x0.y);
        a2 += w0 * bf2f(x0.z); a3 += w0 * bf2f(x0.w);
    }
    float sc = ndv[w];
    ushort4 o;
    o.x = f2bf(a0 * sc); o.y = f2bf(a1 * sc); o.z = f2bf(a2 * sc); o.w = f2bf(a3 * sc);
    *(ushort4*)(y + (size_t)w * 256 + c) = o;
}

// ---------------- edge attention ----------------

__global__ void k_attn(const unsigned short* __restrict__ QKVb,
                       const int* __restrict__ row_ptr, const int* __restrict__ col_src,
                       unsigned short* __restrict__ xo) {
    int w = (int)((blockIdx.x * 256 + threadIdx.x) >> 6);
    if (w >= NN) return;
    int lane = threadIdx.x & 63;
    int c = lane * 4;
    const ushort4 qu = *(const ushort4*)(QKVb + (size_t)w * 768 + c);
    float q0 = bf2f(qu.x), q1 = bf2f(qu.y), q2 = bf2f(qu.z), q3 = bf2f(qu.w);
    float v0 = 0, v1 = 0, v2 = 0, v3 = 0, z = 0;
    int e0 = row_ptr[w], e1 = row_ptr[w + 1];
    int p = e0;
    for (; p + 2 <= e1; p += 2) {
        int s0 = col_src[p], s1 = col_src[p + 1];
        const ushort4 k0 = *(const ushort4*)(QKVb + (size_t)s0 * 768 + 256 + c);
        const ushort4 u0 = *(const ushort4*)(QKVb + (size_t)s0 * 768 + 512 + c);
        const ushort4 k1 = *(const ushort4*)(QKVb + (size_t)s1 * 768 + 256 + c);
        const ushort4 u1 = *(const ushort4*)(QKVb + (size_t)s1 * 768 + 512 + c);
        float t0 = q0 * bf2f(k0.x) + q1 * bf2f(k0.y) + q2 * bf2f(k0.z) + q3 * bf2f(k0.w);
        float t1 = q0 * bf2f(k1.x) + q1 * bf2f(k1.y) + q2 * bf2f(k1.z) + q3 * bf2f(k1.w);
        t0 += __shfl_xor(t0, 1); t1 += __shfl_xor(t1, 1);
        t0 += __shfl_xor(t0, 2); t1 += __shfl_xor(t1, 2);
        t0 += __shfl_xor(t0, 4); t1 += __shfl_xor(t1, 4);
        t0 += __shfl_xor(t0, 8); t1 += __shfl_xor(t1, 8);
        float sc0 = __expf(fminf(fmaxf(t0 * 0.125f, -10.f), 10.f));
        float sc1 = __expf(fminf(fmaxf(t1 * 0.125f, -10.f), 10.f));
        v0 += sc0 * bf2f(u0.x) + sc1 * bf2f(u1.x);
        v1 += sc0 * bf2f(u0.y) + sc1 * bf2f(u1.y);
        v2 += sc0 * bf2f(u0.z) + sc1 * bf2f(u1.z);
        v3 += sc0 * bf2f(u0.w) + sc1 * bf2f(u1.w);
        z += sc0 + sc1;
    }
    if (p < e1) {
        int s0 = col_src[p];
        const ushort4 k0 = *(const ushort4*)(QKVb + (size_t)s0 * 768 + 256 + c);
        const ushort4 u0 = *(const ushort4*)(QKVb + (size_t)s0 * 768 + 512 + c);
        float t0 = q0 * bf2f(k0.x) + q1 * bf2f(k0.y) + q2 * bf2f(k0.z) + q3 * bf2f(k0.w);
        t0 += __shfl_xor(t0, 1);
        t0 += __shfl_xor(t0, 2);
        t0 += __shfl_xor(t0, 4);
        t0 += __shfl_xor(t0, 8);
        float sc0 = __expf(fminf(fmaxf(t0 * 0.125f, -10.f), 10.f));
        v0 += sc0 * bf2f(u0.x); v1 += sc0 * bf2f(u0.y);
        v2 += sc0 * bf2f(u0.z); v3 += sc0 * bf2f(u0.w);
        z += sc0;
    }
    float inv = 1.f / (z + 1e-6f);
    ushort4 o;
    o.x = f2bf(v0 * inv); o.y = f2bf(v1 * inv);
    o.z = f2bf(v2 * inv); o.w = f2bf(v3 * inv);
    *(ushort4*)(xo + (size_t)w * 768 + c) = o;
}

// ---------------- bf16-A 2-term GEMM: C = bf16(relu(A @ W + b)) ----------------
// A bf16 row-major [M,K]; B packed fragment-stream (see k_packw).
// Per buffer (24KB): A granules [0,4096) shorts, Bh [4096,8192), Bl [8192,12288).
// A global load: 4 consecutive lanes cover one row's 64B (coalesced);
//   A LDS write at granule (r>>4)*64+kb*16+(r&15) (4-way conflict, write-only).
// B global load: thread tid reads stream[tid*16B] (perfectly coalesced);
//   B LDS write linear at tid*16B (conflict-free).
// All MFMA fragment reads: granule base + lane (linear, conflict-free).
// Double-buffered; loads for t+1 issued before MFMA of t.

template <int NC>
__global__ __launch_bounds__(256, 3) void k_gemm(
    const unsigned short* __restrict__ A, int lda,
    const unsigned short* __restrict__ Bpk,
    const float* __restrict__ bias,
    unsigned short* __restrict__ C, int ldc, int M, int K) {
    const int P = (M + 127) >> 7;
    const int xcd = blockIdx.x & 7;
    const int j = blockIdx.x >> 3;
    const int ck = (P >> 3) + ((xcd < (P & 7)) ? 1 : 0);
    if (j >= NC * ck) return;
    const int brow = ((j / NC) * 8 + xcd) * 128;
    const int bcol = (j % NC) * 128;
    const int T = K >> 5;

    __shared__ unsigned short smem[24576];   // 48KB: 2 bufs x 12288 shorts

    const int tid = threadIdx.x;
    const int lane = tid & 63;
    const int wid = tid >> 6;
    const int wm = wid & 1, wn = wid >> 1;
    const int fr = lane & 15, kg = lane >> 4;

    const int r0 = tid >> 2, kb = tid & 3;
    const int gr0 = brow + r0, gr1 = gr0 + 64;
    const int ga0 = ((r0 >> 4) << 6) | (kb << 4) | (r0 & 15);   // ga1 = ga0 + 256
    const size_t aoff0 = (size_t)gr0 * lda + kb * 8;
    const size_t aoff1 = (size_t)gr1 * lda + kb * 8;
    const unsigned short* bstream = Bpk + (size_t)(bcol >> 7) * T * 8192;

    f32x4 acc[4][4] = {};
    uint4 av0, av1, bh0v, bh1v, bl0v, bl1v;

#define GLOAD(t_) {                                                            \
    const int k0_ = (t_) << 5;                                                 \
    av0 = make_uint4(0, 0, 0, 0); av1 = make_uint4(0, 0, 0, 0);                \
    if (gr0 < M) av0 = *(const uint4*)(A + aoff0 + k0_);                       \
    if (gr1 < M) av1 = *(const uint4*)(A + aoff1 + k0_);                       \
    const unsigned short* bs_ = bstream + (size_t)(t_) * 8192;                 \
    bh0v = *(const uint4*)(bs_ + tid * 8);                                     \
    bh1v = *(const uint4*)(bs_ + 2048 + tid * 8);                              \
    bl0v = *(const uint4*)(bs_ + 4096 + tid * 8);                              \
    bl1v = *(const uint4*)(bs_ + 6144 + tid * 8); }

#define LWRITE(b_) {                                                           \
    unsigned short* sb_ = smem + (b_) * 12288;                                 \
    *(uint4*)(sb_ + ga0 * 8) = av0;                                            \
    *(uint4*)(sb_ + ga0 * 8 + 2048) = av1;                                     \
    *(uint4*)(sb_ + 4096 + tid * 8) = bh0v;                                    \
    *(uint4*)(sb_ + 6144 + tid * 8) = bh1v;                                    \
    *(uint4*)(sb_ + 8192 + tid * 8) = bl0v;                                    \
    *(uint4*)(sb_ + 10240 + tid * 8) = bl1v; }

    GLOAD(0)
    LWRITE(0)
    for (int t = 0; t < T; ++t) {
        __syncthreads();
        if (t + 1 < T) { GLOAD(t + 1) }
        unsigned short* sb = smem + (t & 1) * 12288;
        s16x8 a[4], bh[4], bl[4];
#pragma unroll
        for (int f = 0; f < 4; ++f) {
            a[f]  = *(const s16x8*)(sb + ((wm * 4 + f) * 64 + lane) * 8);
            bh[f] = *(const s16x8*)(sb + 4096 + ((wn * 4 + f) * 64 + lane) * 8);
            bl[f] = *(const s16x8*)(sb + 8192 + ((wn * 4 + f) * 64 + lane) * 8);
        }
#pragma unroll
        for (int i = 0; i < 4; ++i)
#pragma unroll
            for (int jj = 0; jj < 4; ++jj) {
                acc[i][jj] = __builtin_amdgcn_mfma_f32_16x16x32_bf16(a[i], bh[jj], acc[i][jj], 0, 0, 0);
                acc[i][jj] = __builtin_amdgcn_mfma_f32_16x16x32_bf16(a[i], bl[jj], acc[i][jj], 0, 0, 0);
            }
        if (t + 1 < T) { LWRITE((t + 1) & 1) }
    }
#undef GLOAD
#undef LWRITE

#pragma unroll
    for (int i = 0; i < 4; ++i) {
#pragma unroll
        for (int jj = 0; jj < 4; ++jj) {
            int colG = bcol + wn * 64 + jj * 16 + fr;
            float bb = bias[colG];
#pragma unroll
            for (int r = 0; r < 4; ++r) {
                int row = brow + wm * 64 + i * 16 + kg * 4 + r;
                if (row < M) {
                    float v = fmaxf(acc[i][jj][r] + bb, 0.f);
                    C[(size_t)row * ldc + colG] = f2bf(v);
                }
            }
        }
    }
}

// ---------------- final row-dot + sigmoid ----------------

__global__ void k_final(const unsigned short* __restrict__ h2, const float* __restrict__ W3,
                        const float* __restrict__ b3, float* __restrict__ out) {
    int w = (int)((blockIdx.x * 256 + threadIdx.x) >> 6);
    if (w >= NN) return;
    int lane = threadIdx.x & 63;
    ushort4 hu = *(const ushort4*)(h2 + (size_t)w * 256 + lane * 4);
    float4 ww = *(const float4*)(W3 + lane * 4);
    float p = bf2f(hu.x) * ww.x + bf2f(hu.y) * ww.y + bf2f(hu.z) * ww.z + bf2f(hu.w) * ww.w;
    p += __shfl_xor(p, 1);
    p += __shfl_xor(p, 2);
    p += __shfl_xor(p, 4);
    p += __shfl_xor(p, 8);
    p += __shfl_xor(p, 16);
    p += __shfl_xor(p, 32);
    if (lane == 0) out[w] = 1.f / (1.f + __expf(-(p + b3[0])));
}

__global__ void k_sent(float* __restrict__ out) {
    int i = blockIdx.x * 256 + threadIdx.x;
    if (i < NN) out[i] = 0.5f;
}

// ---------------- launch ----------------

extern "C" void kernel_launch(void* const* d_in, const int* in_sizes, int n_in,
                              void* d_out, int out_size, void* d_ws, size_t ws_size,
                              hipStream_t stream) {
    const float* features = (const float*)d_in[0];
    const int* src = (const int*)d_in[1];
    const int* dst = (const int*)d_in[2];
    const float* Wm = (const float*)d_in[4];
    const float* bm = (const float*)d_in[5];
    const float* W1 = (const float*)d_in[24];
    const float* b1 = (const float*)d_in[25];
    const float* W2 = (const float*)d_in[26];
    const float* b2 = (const float*)d_in[27];
    const float* W3 = (const float*)d_in[28];
    const float* b3 = (const float*)d_in[29];
    float* out = (float*)d_out;

    char* ws = (char*)d_ws;
    size_t off = 0;
    auto alloc = [&](size_t b) -> void* {
        void* p = ws + off;
        off = (off + b + 255) & ~(size_t)255;
        return p;
    };

    int* deg_o = (int*)alloc(NN * 4);   // deg_o and deg_i adjacent: single memset
    int* deg_i = (int*)alloc(NN * 4);
    int* row_ptr = (int*)alloc((NN + 1) * 4);
    int* cursor = (int*)alloc(NN * 4);
    int* col_src = (int*)alloc((size_t)NE * 4);
    float* ewt = (float*)alloc((size_t)NE * 4);
    float* ns = (float*)alloc(NN * 4);
    float* nd = (float*)alloc(NN * 4);
    int* incl = (int*)alloc(NN * 4);
    int* bsum = (int*)alloc(NBLK * 4);
    int* boff = (int*)alloc(NBLK * 4);

    unsigned short* Wmt = (unsigned short*)alloc((size_t)256 * 256 * 2 * 2);
    unsigned short* Wqkvt = (unsigned short*)alloc((size_t)3 * 768 * 256 * 2 * 2);
    unsigned short* W1t = (unsigned short*)alloc((size_t)512 * 768 * 2 * 2);
    unsigned short* W2t = (unsigned short*)alloc((size_t)256 * 512 * 2 * 2);
    float* bqkv = (float*)alloc(3 * 768 * 4);

    unsigned short* fbuf = (unsigned short*)alloc((size_t)NN * 256 * 2);   // 25.6 MB
    unsigned short* QKVb = (unsigned short*)alloc((size_t)NN * 768 * 2);   // 76.8 MB
    unsigned short* y = (unsigned short*)alloc((size_t)NN * 256 * 2);      // 25.6 MB
    unsigned short* xcat = (unsigned short*)alloc((size_t)NN * 768 * 2);   // 76.8 MB

    unsigned short* x0b = xcat;   // [NN,256]; dead before attn1 overwrites xcat
    unsigned short* h1 = QKVb;    // [NN,512]; QKVb dead after attn3
    unsigned short* h2 = y;       // [NN,256]; y dead after layer-3 QKV gemm

    (void)in_sizes; (void)n_in; (void)out_size;

    if (off > ws_size) {
        k_sent<<<(NN + 255) / 256, 256, 0, stream>>>(out);
        return;
    }

    hipMemsetAsync(deg_o, 0, (size_t)((char*)deg_i - (char*)deg_o) + NN * 4, stream);
    k_deg<<<(NE + 255) / 256, 256, 0, stream>>>(src, dst, deg_o, deg_i);
    k_scanA<<<NBLK, 256, 0, stream>>>(deg_i, incl, bsum);
    k_scanB<<<1, 256, 0, stream>>>(bsum, boff, row_ptr);
    k_scanC<<<NBLK, 256, 0, stream>>>(deg_o, deg_i, incl, boff, row_ptr, cursor, ns, nd);
    k_fill<<<(NE + 255) / 256, 256, 0, stream>>>(src, dst, ns, cursor, col_src, ewt);

    QkvPtrs qp;
    BiasPtrs bp;
    for (int l = 0; l < 3; ++l)
        for (int m = 0; m < 3; ++m) {
            qp.w[l * 3 + m] = (const float*)d_in[6 + l * 6 + m * 2];
            bp.b[l * 3 + m] = (const float*)d_in[7 + l * 6 + m * 2];
        }
    qp.out = Wqkvt;
    bp.dst = bqkv;
    k_packqkv<<<dim3(192, 3), 256, 0, stream>>>(qp);
    k_bcat<<<9, 256, 0, stream>>>(bp);
    k_packw<<<64, 256, 0, stream>>>(Wm, Wmt, 256, 256, 16384);
    k_packw<<<384, 256, 0, stream>>>(W1, W1t, 768, 512, 98304);
    k_packw<<<128, 256, 0, stream>>>(W2, W2t, 512, 256, 32768);

    k_cvt<<<(NN * 64 + 255) / 256, 256, 0, stream>>>(features, fbuf, NN * 64);

    const int P8 = ((NN + 127) / 128 + 7) / 8;  // 49

    // x0b = bf16(relu(features @ Wm + bm))
    k_gemm<2><<<8 * 2 * P8, 256, 0, stream>>>(fbuf, 256, Wmt, bm, x0b, 256, NN, 256);

    const unsigned short* xin = x0b;
    int ldx = 256;
    for (int l = 0; l < 3; ++l) {
        k_prop<<<12500, 256, 0, stream>>>(xin, ldx, row_ptr, col_src, ewt, nd, y);
        k_gemm<6><<<8 * 6 * P8, 256, 0, stream>>>(y, 256, Wqkvt + (size_t)l * 393216,
                                                  bqkv + l * 768, QKVb, 768, NN, 256);
        k_attn<<<12500, 256, 0, stream>>>(QKVb, row_ptr, col_src, xcat + 256 * l);
        xin = xcat + 256 * l;
        ldx = 768;
    }

    // MLP head
    k_gemm<4><<<8 * 4 * P8, 256, 0, stream>>>(xcat, 768, W1t, b1, h1, 512, NN, 768);
    k_gemm<2><<<8 * 2 * P8, 256, 0, stream>>>(h1, 512, W2t, b2, h2, 256, NN, 512);
    k_final<<<12500, 256, 0, stream>>>(h2, W3, b3, out);
}

// Round 10
// 1032.386 us; speedup vs baseline: 1.3154x; 1.0083x over previous
//
#include <hip/hip_runtime.h>
#include <stdint.h>

#define NN 50000
#define NE 800000
#define NBLK 196   // ceil(NN/256)

typedef float f32x4 __attribute__((ext_vector_type(4)));
typedef short s16x8 __attribute__((ext_vector_type(8)));

__device__ __forceinline__ float bf2f(unsigned short u) {
    union { unsigned int i; float f; } v; v.i = ((unsigned int)u) << 16; return v.f;
}
__device__ __forceinline__ unsigned short f2bf(float x) {
    union { float f; unsigned int i; } v; v.f = x;
    unsigned int r = v.i + 0x7FFFu + ((v.i >> 16) & 1u);
    return (unsigned short)(r >> 16);
}

// ---------------- graph preprocessing ----------------

__global__ void k_deg(const int* __restrict__ src, const int* __restrict__ dst,
                      int* __restrict__ dego, int* __restrict__ degi) {
    int e = blockIdx.x * 256 + threadIdx.x;
    if (e < NE) {
        atomicAdd(&dego[src[e]], 1);
        atomicAdd(&degi[dst[e]], 1);
    }
}

__global__ void k_scanA(const int* __restrict__ deg, int* __restrict__ incl,
                        int* __restrict__ bsum) {
    __shared__ int sm[256];
    int t = threadIdx.x, i = blockIdx.x * 256 + t;
    int v = (i < NN) ? deg[i] : 0;
    sm[t] = v;
    __syncthreads();
#pragma unroll
    for (int off = 1; off < 256; off <<= 1) {
        int tv = (t >= off) ? sm[t - off] : 0;
        __syncthreads();
        sm[t] += tv;
        __syncthreads();
    }
    if (i < NN) incl[i] = sm[t];
    if (t == 255) bsum[blockIdx.x] = sm[255];
}

__global__ void k_scanB(const int* __restrict__ bsum, int* __restrict__ boff,
                        int* __restrict__ row_ptr) {
    __shared__ int sm[256];
    int t = threadIdx.x;
    int v = (t < NBLK) ? bsum[t] : 0;
    sm[t] = v;
    __syncthreads();
#pragma unroll
    for (int off = 1; off < 256; off <<= 1) {
        int tv = (t >= off) ? sm[t - off] : 0;
        __syncthreads();
        sm[t] += tv;
        __syncthreads();
    }
    if (t < NBLK) boff[t] = sm[t] - v;  // exclusive
    if (t == 255) row_ptr[NN] = sm[255];
}

__global__ void k_scanC(const int* __restrict__ dego, const int* __restrict__ degi,
                        const int* __restrict__ incl, const int* __restrict__ boff,
                        int* __restrict__ row_ptr, int* __restrict__ cursor,
                        float* __restrict__ ns, float* __restrict__ nd) {
    int i = blockIdx.x * 256 + threadIdx.x;
    if (i < NN) {
        int ex = boff[blockIdx.x] + incl[i] - degi[i];
        row_ptr[i] = ex;
        cursor[i] = ex;
        ns[i] = dego[i] > 0 ? rsqrtf((float)dego[i]) : 0.f;
        nd[i] = degi[i] > 0 ? rsqrtf((float)degi[i]) : 0.f;
    }
}

__global__ void k_fill(const int* __restrict__ src, const int* __restrict__ dst,
                       const float* __restrict__ ns,
                       int* __restrict__ cursor, int* __restrict__ col_src,
                       float* __restrict__ ewt) {
    int e = blockIdx.x * 256 + threadIdx.x;
    if (e < NE) {
        int s = src[e];
        int slot = atomicAdd(&cursor[dst[e]], 1);
        col_src[slot] = s;
        ewt[slot] = ns[s];
    }
}

// ---------------- weight packing: fragment-stream order ----------------
// Packed stream for W^T [N,K]: tile cb x K-step t x hl x granule g x elem e.
// Granule g(r,kb) = (r>>4)*64+kb*16+(r&15); short index ((cb*T+t)*1024+hl*512+g)*8+e.

__global__ void k_packw(const float* __restrict__ W, unsigned short* __restrict__ out,
                        int K, int N, int ngran) {
    int gid = blockIdx.x * 256 + threadIdx.x;
    if (gid >= ngran) return;
    int T1024 = (K >> 5) << 10;
    int cb = gid / T1024, rem = gid - cb * T1024;
    int t = rem >> 10, rem2 = rem & 1023;
    int hl = rem2 >> 9, g = rem2 & 511;
    int r = ((g >> 6) << 4) | (g & 15);
    int kb = (g >> 4) & 3;
    int n = cb * 128 + r;
    int k = t * 32 + kb * 8;
    unsigned short vals[8];
#pragma unroll
    for (int e = 0; e < 8; ++e) {
        float w = W[(size_t)(k + e) * N + n];
        unsigned short h = f2bf(w);
        vals[e] = hl ? f2bf(w - bf2f(h)) : h;
    }
    *(ushort4*)(out + (size_t)gid * 8) = make_ushort4(vals[0], vals[1], vals[2], vals[3]);
    *(ushort4*)(out + (size_t)gid * 8 + 4) = make_ushort4(vals[4], vals[5], vals[6], vals[7]);
}

struct QkvPtrs { const float* w[9]; unsigned short* out; };

__global__ void k_packqkv(QkvPtrs P) {
    int layer = blockIdx.y;
    int gid = blockIdx.x * 256 + threadIdx.x;       // 0..49151
    int cb = gid >> 13, rem = gid & 8191;           // T*1024 = 8192
    int t = rem >> 10, rem2 = rem & 1023;
    int hl = rem2 >> 9, g = rem2 & 511;
    int r = ((g >> 6) << 4) | (g & 15);
    int kb = (g >> 4) & 3;
    int n = cb * 128 + r;
    int which = n >> 8, nl = n & 255;
    int k = t * 32 + kb * 8;
    const float* W = P.w[layer * 3 + which];
    unsigned short vals[8];
#pragma unroll
    for (int e = 0; e < 8; ++e) {
        float w = W[(size_t)(k + e) * 256 + nl];
        unsigned short h = f2bf(w);
        vals[e] = hl ? f2bf(w - bf2f(h)) : h;
    }
    size_t o = ((size_t)layer * 49152 + gid) * 8;
    *(ushort4*)(P.out + o) = make_ushort4(vals[0], vals[1], vals[2], vals[3]);
    *(ushort4*)(P.out + o + 4) = make_ushort4(vals[4], vals[5], vals[6], vals[7]);
}

struct BiasPtrs { const float* b[9]; float* dst; };

__global__ void k_bcat(BiasPtrs P) {
    int m = blockIdx.x;
    int layer = m / 3, which = m - layer * 3;
    P.dst[layer * 768 + which * 256 + (int)threadIdx.x] = P.b[m][threadIdx.x];
}

__global__ void k_cvt(const float* __restrict__ in, unsigned short* __restrict__ ob, int n4) {
    int i = blockIdx.x * 256 + threadIdx.x;
    if (i < n4) {
        float4 v = ((const float4*)in)[i];
        ushort4 o;
        o.x = f2bf(v.x); o.y = f2bf(v.y); o.z = f2bf(v.z); o.w = f2bf(v.w);
        ((ushort4*)ob)[i] = o;
    }
}

// ---------------- GCN propagate: y[d] = nd[d] * sum ewt[e] * x[src[e]] ----------------
// Lane-split: lanes 0-31 even-slot edges, 32-63 odd-slot; each lane 8 cols via
// one 16B load. x2 pair unroll (4 edges in flight). shfl_xor(32) combine.

__global__ void k_prop(const unsigned short* __restrict__ xb, int ldx,
                       const int* __restrict__ row_ptr, const int* __restrict__ col_src,
                       const float* __restrict__ ewt, const float* __restrict__ ndv,
                       unsigned short* __restrict__ y) {
    int w = (int)((blockIdx.x * 256 + threadIdx.x) >> 6);
    if (w >= NN) return;
    int lane = threadIdx.x & 63;
    int half = lane >> 5;
    int c = (lane & 31) * 8;
    float a[8] = {};
    int e0 = row_ptr[w], e1 = row_ptr[w + 1];
    int p = e0;
    for (; p + 4 <= e1; p += 4) {
        int pa = p + half, pb = p + 2 + half;
        int sa = col_src[pa], sb = col_src[pb];
        float wa = ewt[pa], wb = ewt[pb];
        uint4 va = *(const uint4*)(xb + (size_t)sa * ldx + c);
        uint4 vb = *(const uint4*)(xb + (size_t)sb * ldx + c);
        const unsigned short* ua = (const unsigned short*)&va;
        const unsigned short* ub = (const unsigned short*)&vb;
#pragma unroll
        for (int i = 0; i < 8; ++i)
            a[i] += wa * bf2f(ua[i]) + wb * bf2f(ub[i]);
    }
    if (p + 2 <= e1) {
        int pa = p + half;
        int sa = col_src[pa];
        float wa = ewt[pa];
        uint4 va = *(const uint4*)(xb + (size_t)sa * ldx + c);
        const unsigned short* ua = (const unsigned short*)&va;
#pragma unroll
        for (int i = 0; i < 8; ++i) a[i] += wa * bf2f(ua[i]);
        p += 2;
    }
    if (p < e1 && half == 0) {      // final odd edge: lanes 0-31 only
        int sa = col_src[p];
        float wa = ewt[p];
        uint4 va = *(const uint4*)(xb + (size_t)sa * ldx + c);
        const unsigned short* ua = (const unsigned short*)&va;
#pragma unroll
        for (int i = 0; i < 8; ++i) a[i] += wa * bf2f(ua[i]);
    }
#pragma unroll
    for (int i = 0; i < 8; ++i) a[i] += __shfl_xor(a[i], 32);
    if (lane < 32) {
        float sc = ndv[w];
        unsigned short us[8];
#pragma unroll
        for (int i = 0; i < 8; ++i) us[i] = f2bf(a[i] * sc);
        *(uint4*)(y + (size_t)w * 256 + c) = *(const uint4*)us;
    }
}

// ---------------- edge attention ----------------
// QKVb [NN,768] bf16: Q 0-255 plain; cols 256-767 KV-INTERLEAVED per 4-dim
// chunk: K[c..c+3] at 256+2c, V[c..c+3] at 256+2c+4. One 16B load per edge
// per lane. 4-edge unroll.

__global__ void k_attn(const unsigned short* __restrict__ QKVb,
                       const int* __restrict__ row_ptr, const int* __restrict__ col_src,
                       unsigned short* __restrict__ xo) {
    int w = (int)((blockIdx.x * 256 + threadIdx.x) >> 6);
    if (w >= NN) return;
    int lane = threadIdx.x & 63;
    int c = lane * 4;
    const int kvo = 256 + 2 * c;
    const ushort4 qu = *(const ushort4*)(QKVb + (size_t)w * 768 + c);
    float q0 = bf2f(qu.x), q1 = bf2f(qu.y), q2 = bf2f(qu.z), q3 = bf2f(qu.w);
    float v0 = 0, v1 = 0, v2 = 0, v3 = 0, z = 0;
    int e0 = row_ptr[w], e1 = row_ptr[w + 1];
    int p = e0;
    for (; p + 4 <= e1; p += 4) {
        int s0 = col_src[p], s1 = col_src[p + 1], s2 = col_src[p + 2], s3 = col_src[p + 3];
        uint4 kv0 = *(const uint4*)(QKVb + (size_t)s0 * 768 + kvo);
        uint4 kv1 = *(const uint4*)(QKVb + (size_t)s1 * 768 + kvo);
        uint4 kv2 = *(const uint4*)(QKVb + (size_t)s2 * 768 + kvo);
        uint4 kv3 = *(const uint4*)(QKVb + (size_t)s3 * 768 + kvo);
        const unsigned short* a0 = (const unsigned short*)&kv0;
        const unsigned short* a1 = (const unsigned short*)&kv1;
        const unsigned short* a2 = (const unsigned short*)&kv2;
        const unsigned short* a3 = (const unsigned short*)&kv3;
        float t0 = q0 * bf2f(a0[0]) + q1 * bf2f(a0[1]) + q2 * bf2f(a0[2]) + q3 * bf2f(a0[3]);
        float t1 = q0 * bf2f(a1[0]) + q1 * bf2f(a1[1]) + q2 * bf2f(a1[2]) + q3 * bf2f(a1[3]);
        float t2 = q0 * bf2f(a2[0]) + q1 * bf2f(a2[1]) + q2 * bf2f(a2[2]) + q3 * bf2f(a2[3]);
        float t3 = q0 * bf2f(a3[0]) + q1 * bf2f(a3[1]) + q2 * bf2f(a3[2]) + q3 * bf2f(a3[3]);
        t0 += __shfl_xor(t0, 1); t1 += __shfl_xor(t1, 1); t2 += __shfl_xor(t2, 1); t3 += __shfl_xor(t3, 1);
        t0 += __shfl_xor(t0, 2); t1 += __shfl_xor(t1, 2); t2 += __shfl_xor(t2, 2); t3 += __shfl_xor(t3, 2);
        t0 += __shfl_xor(t0, 4); t1 += __shfl_xor(t1, 4); t2 += __shfl_xor(t2, 4); t3 += __shfl_xor(t3, 4);
        t0 += __shfl_xor(t0, 8); t1 += __shfl_xor(t1, 8); t2 += __shfl_xor(t2, 8); t3 += __shfl_xor(t3, 8);
        float sc0 = __expf(fminf(fmaxf(t0 * 0.125f, -10.f), 10.f));
        float sc1 = __expf(fminf(fmaxf(t1 * 0.125f, -10.f), 10.f));
        float sc2 = __expf(fminf(fmaxf(t2 * 0.125f, -10.f), 10.f));
        float sc3 = __expf(fminf(fmaxf(t3 * 0.125f, -10.f), 10.f));
        v0 += sc0 * bf2f(a0[4]) + sc1 * bf2f(a1[4]) + sc2 * bf2f(a2[4]) + sc3 * bf2f(a3[4]);
        v1 += sc0 * bf2f(a0[5]) + sc1 * bf2f(a1[5]) + sc2 * bf2f(a2[5]) + sc3 * bf2f(a3[5]);
        v2 += sc0 * bf2f(a0[6]) + sc1 * bf2f(a1[6]) + sc2 * bf2f(a2[6]) + sc3 * bf2f(a3[6]);
        v3 += sc0 * bf2f(a0[7]) + sc1 * bf2f(a1[7]) + sc2 * bf2f(a2[7]) + sc3 * bf2f(a3[7]);
        z += sc0 + sc1 + sc2 + sc3;
    }
    for (; p < e1; ++p) {
        int s0 = col_src[p];
        uint4 kv0 = *(const uint4*)(QKVb + (size_t)s0 * 768 + kvo);
        const unsigned short* a0 = (const unsigned short*)&kv0;
        float t0 = q0 * bf2f(a0[0]) + q1 * bf2f(a0[1]) + q2 * bf2f(a0[2]) + q3 * bf2f(a0[3]);
        t0 += __shfl_xor(t0, 1);
        t0 += __shfl_xor(t0, 2);
        t0 += __shfl_xor(t0, 4);
        t0 += __shfl_xor(t0, 8);
        float sc0 = __expf(fminf(fmaxf(t0 * 0.125f, -10.f), 10.f));
        v0 += sc0 * bf2f(a0[4]); v1 += sc0 * bf2f(a0[5]);
        v2 += sc0 * bf2f(a0[6]); v3 += sc0 * bf2f(a0[7]);
        z += sc0;
    }
    float inv = 1.f / (z + 1e-6f);
    ushort4 o;
    o.x = f2bf(v0 * inv); o.y = f2bf(v1 * inv);
    o.z = f2bf(v2 * inv); o.w = f2bf(v3 * inv);
    *(ushort4*)(xo + (size_t)w * 768 + c) = o;
}

// ---------------- bf16-A 2-term GEMM: C = bf16(relu(A @ W + b)) ----------------
// A row-major; B packed fragment-stream. Decoupled staging (R9 layout, verified
// 0 read conflicts). KVPACK=1: cols 256-767 remapped to KV-interleaved layout.

template <int NC, int KVPACK>
__global__ __launch_bounds__(256, 3) void k_gemm(
    const unsigned short* __restrict__ A, int lda,
    const unsigned short* __restrict__ Bpk,
    const float* __restrict__ bias,
    unsigned short* __restrict__ C, int ldc, int M, int K) {
    const int P = (M + 127) >> 7;
    const int xcd = blockIdx.x & 7;
    const int j = blockIdx.x >> 3;
    const int ck = (P >> 3) + ((xcd < (P & 7)) ? 1 : 0);
    if (j >= NC * ck) return;
    const int brow = ((j / NC) * 8 + xcd) * 128;
    const int bcol = (j % NC) * 128;
    const int T = K >> 5;

    __shared__ unsigned short smem[24576];   // 48KB: 2 bufs x 12288 shorts

    const int tid = threadIdx.x;
    const int lane = tid & 63;
    const int wid = tid >> 6;
    const int wm = wid & 1, wn = wid >> 1;
    const int fr = lane & 15, kg = lane >> 4;

    const int r0 = tid >> 2, kb = tid & 3;
    const int gr0 = brow + r0, gr1 = gr0 + 64;
    const int ga0 = ((r0 >> 4) << 6) | (kb << 4) | (r0 & 15);
    const size_t aoff0 = (size_t)gr0 * lda + kb * 8;
    const size_t aoff1 = (size_t)gr1 * lda + kb * 8;
    const unsigned short* bstream = Bpk + (size_t)(bcol >> 7) * T * 8192;

    f32x4 acc[4][4] = {};
    uint4 av0, av1, bh0v, bh1v, bl0v, bl1v;

#define GLOAD(t_) {                                                            \
    const int k0_ = (t_) << 5;                                                 \
    av0 = make_uint4(0, 0, 0, 0); av1 = make_uint4(0, 0, 0, 0);                \
    if (gr0 < M) av0 = *(const uint4*)(A + aoff0 + k0_);                       \
    if (gr1 < M) av1 = *(const uint4*)(A + aoff1 + k0_);                       \
    const unsigned short* bs_ = bstream + (size_t)(t_) * 8192;                 \
    bh0v = *(const uint4*)(bs_ + tid * 8);                                     \
    bh1v = *(const uint4*)(bs_ + 2048 + tid * 8);                              \
    bl0v = *(const uint4*)(bs_ + 4096 + tid * 8);                              \
    bl1v = *(const uint4*)(bs_ + 6144 + tid * 8); }

#define LWRITE(b_) {                                                           \
    unsigned short* sb_ = smem + (b_) * 12288;                                 \
    *(uint4*)(sb_ + ga0 * 8) = av0;                                            \
    *(uint4*)(sb_ + ga0 * 8 + 2048) = av1;                                     \
    *(uint4*)(sb_ + 4096 + tid * 8) = bh0v;                                    \
    *(uint4*)(sb_ + 6144 + tid * 8) = bh1v;                                    \
    *(uint4*)(sb_ + 8192 + tid * 8) = bl0v;                                    \
    *(uint4*)(sb_ + 10240 + tid * 8) = bl1v; }

    GLOAD(0)
    LWRITE(0)
    for (int t = 0; t < T; ++t) {
        __syncthreads();
        if (t + 1 < T) { GLOAD(t + 1) }
        unsigned short* sb = smem + (t & 1) * 12288;
        s16x8 a[4], bh[4], bl[4];
#pragma unroll
        for (int f = 0; f < 4; ++f) {
            a[f]  = *(const s16x8*)(sb + ((wm * 4 + f) * 64 + lane) * 8);
            bh[f] = *(const s16x8*)(sb + 4096 + ((wn * 4 + f) * 64 + lane) * 8);
            bl[f] = *(const s16x8*)(sb + 8192 + ((wn * 4 + f) * 64 + lane) * 8);
        }
#pragma unroll
        for (int i = 0; i < 4; ++i)
#pragma unroll
            for (int jj = 0; jj < 4; ++jj) {
                acc[i][jj] = __builtin_amdgcn_mfma_f32_16x16x32_bf16(a[i], bh[jj], acc[i][jj], 0, 0, 0);
                acc[i][jj] = __builtin_amdgcn_mfma_f32_16x16x32_bf16(a[i], bl[jj], acc[i][jj], 0, 0, 0);
            }
        if (t + 1 < T) { LWRITE((t + 1) & 1) }
    }
#undef GLOAD
#undef LWRITE

#pragma unroll
    for (int i = 0; i < 4; ++i) {
#pragma unroll
        for (int jj = 0; jj < 4; ++jj) {
            int colG = bcol + wn * 64 + jj * 16 + fr;
            float bb = bias[colG];
            int dcol = colG;
            if (KVPACK && colG >= 256) {
                int u = colG - 256;
                int kv = u >> 8;         // 0 = K, 1 = V
                int uu = u & 255;
                dcol = 256 + ((uu & ~3) << 1) + (kv << 2) + (uu & 3);
            }
#pragma unroll
            for (int r = 0; r < 4; ++r) {
                int row = brow + wm * 64 + i * 16 + kg * 4 + r;
                if (row < M) {
                    float v = fmaxf(acc[i][jj][r] + bb, 0.f);
                    C[(size_t)row * ldc + dcol] = f2bf(v);
                }
            }
        }
    }
}

// ---------------- final row-dot + sigmoid ----------------

__global__ void k_final(const unsigned short* __restrict__ h2, const float* __restrict__ W3,
                        const float* __restrict__ b3, float* __restrict__ out) {
    int w = (int)((blockIdx.x * 256 + threadIdx.x) >> 6);
    if (w >= NN) return;
    int lane = threadIdx.x & 63;
    ushort4 hu = *(const ushort4*)(h2 + (size_t)w * 256 + lane * 4);
    float4 ww = *(const float4*)(W3 + lane * 4);
    float p = bf2f(hu.x) * ww.x + bf2f(hu.y) * ww.y + bf2f(hu.z) * ww.z + bf2f(hu.w) * ww.w;
    p += __shfl_xor(p, 1);
    p += __shfl_xor(p, 2);
    p += __shfl_xor(p, 4);
    p += __shfl_xor(p, 8);
    p += __shfl_xor(p, 16);
    p += __shfl_xor(p, 32);
    if (lane == 0) out[w] = 1.f / (1.f + __expf(-(p + b3[0])));
}

__global__ void k_sent(float* __restrict__ out) {
    int i = blockIdx.x * 256 + threadIdx.x;
    if (i < NN) out[i] = 0.5f;
}

// ---------------- launch ----------------

extern "C" void kernel_launch(void* const* d_in, const int* in_sizes, int n_in,
                              void* d_out, int out_size, void* d_ws, size_t ws_size,
                              hipStream_t stream) {
    const float* features = (const float*)d_in[0];
    const int* src = (const int*)d_in[1];
    const int* dst = (const int*)d_in[2];
    const float* Wm = (const float*)d_in[4];
    const float* bm = (const float*)d_in[5];
    const float* W1 = (const float*)d_in[24];
    const float* b1 = (const float*)d_in[25];
    const float* W2 = (const float*)d_in[26];
    const float* b2 = (const float*)d_in[27];
    const float* W3 = (const float*)d_in[28];
    const float* b3 = (const float*)d_in[29];
    float* out = (float*)d_out;

    char* ws = (char*)d_ws;
    size_t off = 0;
    auto alloc = [&](size_t b) -> void* {
        void* p = ws + off;
        off = (off + b + 255) & ~(size_t)255;
        return p;
    };

    int* deg_o = (int*)alloc(NN * 4);
    int* deg_i = (int*)alloc(NN * 4);
    int* row_ptr = (int*)alloc((NN + 1) * 4);
    int* cursor = (int*)alloc(NN * 4);
    int* col_src = (int*)alloc((size_t)NE * 4);
    float* ewt = (float*)alloc((size_t)NE * 4);
    float* ns = (float*)alloc(NN * 4);
    float* nd = (float*)alloc(NN * 4);
    int* incl = (int*)alloc(NN * 4);
    int* bsum = (int*)alloc(NBLK * 4);
    int* boff = (int*)alloc(NBLK * 4);

    unsigned short* Wmt = (unsigned short*)alloc((size_t)256 * 256 * 2 * 2);
    unsigned short* Wqkvt = (unsigned short*)alloc((size_t)3 * 768 * 256 * 2 * 2);
    unsigned short* W1t = (unsigned short*)alloc((size_t)512 * 768 * 2 * 2);
    unsigned short* W2t = (unsigned short*)alloc((size_t)256 * 512 * 2 * 2);
    float* bqkv = (float*)alloc(3 * 768 * 4);

    unsigned short* fbuf = (unsigned short*)alloc((size_t)NN * 256 * 2);   // 25.6 MB
    unsigned short* QKVb = (unsigned short*)alloc((size_t)NN * 768 * 2);   // 76.8 MB
    unsigned short* y = (unsigned short*)alloc((size_t)NN * 256 * 2);      // 25.6 MB
    unsigned short* xcat = (unsigned short*)alloc((size_t)NN * 768 * 2);   // 76.8 MB

    unsigned short* x0b = xcat;   // [NN,256]; dead before attn1 overwrites xcat
    unsigned short* h1 = QKVb;    // [NN,512]; QKVb dead after attn3
    unsigned short* h2 = y;       // [NN,256]; y dead after layer-3 QKV gemm

    (void)in_sizes; (void)n_in; (void)out_size;

    if (off > ws_size) {
        k_sent<<<(NN + 255) / 256, 256, 0, stream>>>(out);
        return;
    }

    hipMemsetAsync(deg_o, 0, (size_t)((char*)deg_i - (char*)deg_o) + NN * 4, stream);
    k_deg<<<(NE + 255) / 256, 256, 0, stream>>>(src, dst, deg_o, deg_i);
    k_scanA<<<NBLK, 256, 0, stream>>>(deg_i, incl, bsum);
    k_scanB<<<1, 256, 0, stream>>>(bsum, boff, row_ptr);
    k_scanC<<<NBLK, 256, 0, stream>>>(deg_o, deg_i, incl, boff, row_ptr, cursor, ns, nd);
    k_fill<<<(NE + 255) / 256, 256, 0, stream>>>(src, dst, ns, cursor, col_src, ewt);

    QkvPtrs qp;
    BiasPtrs bp;
    for (int l = 0; l < 3; ++l)
        for (int m = 0; m < 3; ++m) {
            qp.w[l * 3 + m] = (const float*)d_in[6 + l * 6 + m * 2];
            bp.b[l * 3 + m] = (const float*)d_in[7 + l * 6 + m * 2];
        }
    qp.out = Wqkvt;
    bp.dst = bqkv;
    k_packqkv<<<dim3(192, 3), 256, 0, stream>>>(qp);
    k_bcat<<<9, 256, 0, stream>>>(bp);
    k_packw<<<64, 256, 0, stream>>>(Wm, Wmt, 256, 256, 16384);
    k_packw<<<384, 256, 0, stream>>>(W1, W1t, 768, 512, 98304);
    k_packw<<<128, 256, 0, stream>>>(W2, W2t, 512, 256, 32768);

    k_cvt<<<(NN * 64 + 255) / 256, 256, 0, stream>>>(features, fbuf, NN * 64);

    const int P8 = ((NN + 127) / 128 + 7) / 8;  // 49

    // x0b = bf16(relu(features @ Wm + bm))
    k_gemm<2, 0><<<8 * 2 * P8, 256, 0, stream>>>(fbuf, 256, Wmt, bm, x0b, 256, NN, 256);

    const unsigned short* xin = x0b;
    int ldx = 256;
    for (int l = 0; l < 3; ++l) {
        k_prop<<<12500, 256, 0, stream>>>(xin, ldx, row_ptr, col_src, ewt, nd, y);
        k_gemm<6, 1><<<8 * 6 * P8, 256, 0, stream>>>(y, 256, Wqkvt + (size_t)l * 393216,
                                                     bqkv + l * 768, QKVb, 768, NN, 256);
        k_attn<<<12500, 256, 0, stream>>>(QKVb, row_ptr, col_src, xcat + 256 * l);
        xin = xcat + 256 * l;
        ldx = 768;
    }

    // MLP head
    k_gemm<4, 0><<<8 * 4 * P8, 256, 0, stream>>>(xcat, 768, W1t, b1, h1, 512, NN, 768);
    k_gemm<2, 0><<<8 * 2 * P8, 256, 0, stream>>>(h1, 512, W2t, b2, h2, 256, NN, 512);
    k_final<<<12500, 256, 0, stream>>>(h2, W3, b3, out);
}

// Round 11
// 927.653 us; speedup vs baseline: 1.4639x; 1.1129x over previous
//
#include <hip/hip_runtime.h>
#include <hip/hip_fp8.h>
#include <stdint.h>

#define NN 50000
#define NE 800000
#define NBLK 196   // ceil(NN/256)

typedef float f32x4 __attribute__((ext_vector_type(4)));
typedef short s16x8 __attribute__((ext_vector_type(8)));

__device__ __forceinline__ float bf2f(unsigned short u) {
    union { unsigned int i; float f; } v; v.i = ((unsigned int)u) << 16; return v.f;
}
__device__ __forceinline__ unsigned short f2bf(float x) {
    union { float f; unsigned int i; } v; v.f = x;
    unsigned int r = v.i + 0x7FFFu + ((v.i >> 16) & 1u);
    return (unsigned short)(r >> 16);
}
__device__ __forceinline__ unsigned char f2fp8(float x) {
    __hip_fp8_e4m3 t(x);
    return (unsigned char)t.__x;
}
__device__ __forceinline__ float fp82f(unsigned char u) {
    __hip_fp8_e4m3 t;
    t.__x = (__hip_fp8_storage_t)u;
    return (float)t;
}

// ---------------- graph preprocessing ----------------

__global__ void k_deg(const int* __restrict__ src, const int* __restrict__ dst,
                      int* __restrict__ dego, int* __restrict__ degi) {
    int e = blockIdx.x * 256 + threadIdx.x;
    if (e < NE) {
        atomicAdd(&dego[src[e]], 1);
        atomicAdd(&degi[dst[e]], 1);
    }
}

__global__ void k_scanA(const int* __restrict__ deg, int* __restrict__ incl,
                        int* __restrict__ bsum) {
    __shared__ int sm[256];
    int t = threadIdx.x, i = blockIdx.x * 256 + t;
    int v = (i < NN) ? deg[i] : 0;
    sm[t] = v;
    __syncthreads();
#pragma unroll
    for (int off = 1; off < 256; off <<= 1) {
        int tv = (t >= off) ? sm[t - off] : 0;
        __syncthreads();
        sm[t] += tv;
        __syncthreads();
    }
    if (i < NN) incl[i] = sm[t];
    if (t == 255) bsum[blockIdx.x] = sm[255];
}

__global__ void k_scanB(const int* __restrict__ bsum, int* __restrict__ boff,
                        int* __restrict__ row_ptr) {
    __shared__ int sm[256];
    int t = threadIdx.x;
    int v = (t < NBLK) ? bsum[t] : 0;
    sm[t] = v;
    __syncthreads();
#pragma unroll
    for (int off = 1; off < 256; off <<= 1) {
        int tv = (t >= off) ? sm[t - off] : 0;
        __syncthreads();
        sm[t] += tv;
        __syncthreads();
    }
    if (t < NBLK) boff[t] = sm[t] - v;  // exclusive
    if (t == 255) row_ptr[NN] = sm[255];
}

__global__ void k_scanC(const int* __restrict__ dego, const int* __restrict__ degi,
                        const int* __restrict__ incl, const int* __restrict__ boff,
                        int* __restrict__ row_ptr, int* __restrict__ cursor,
                        float* __restrict__ ns, float* __restrict__ nd) {
    int i = blockIdx.x * 256 + threadIdx.x;
    if (i < NN) {
        int ex = boff[blockIdx.x] + incl[i] - degi[i];
        row_ptr[i] = ex;
        cursor[i] = ex;
        ns[i] = dego[i] > 0 ? rsqrtf((float)dego[i]) : 0.f;
        nd[i] = degi[i] > 0 ? rsqrtf((float)degi[i]) : 0.f;
    }
}

__global__ void k_fill(const int* __restrict__ src, const int* __restrict__ dst,
                       const float* __restrict__ ns,
                       int* __restrict__ cursor, int* __restrict__ col_src,
                       float* __restrict__ ewt) {
    int e = blockIdx.x * 256 + threadIdx.x;
    if (e < NE) {
        int s = src[e];
        int slot = atomicAdd(&cursor[dst[e]], 1);
        col_src[slot] = s;
        ewt[slot] = ns[s];
    }
}

// ---------------- weight packing: fragment-stream order ----------------
// Granule g(r,kb) = (r>>4)*64+kb*16+(r&15); short index ((cb*T+t)*1024+hl*512+g)*8+e.

__global__ void k_packw(const float* __restrict__ W, unsigned short* __restrict__ out,
                        int K, int N, int ngran) {
    int gid = blockIdx.x * 256 + threadIdx.x;
    if (gid >= ngran) return;
    int T1024 = (K >> 5) << 10;
    int cb = gid / T1024, rem = gid - cb * T1024;
    int t = rem >> 10, rem2 = rem & 1023;
    int hl = rem2 >> 9, g = rem2 & 511;
    int r = ((g >> 6) << 4) | (g & 15);
    int kb = (g >> 4) & 3;
    int n = cb * 128 + r;
    int k = t * 32 + kb * 8;
    unsigned short vals[8];
#pragma unroll
    for (int e = 0; e < 8; ++e) {
        float w = W[(size_t)(k + e) * N + n];
        unsigned short h = f2bf(w);
        vals[e] = hl ? f2bf(w - bf2f(h)) : h;
    }
    *(ushort4*)(out + (size_t)gid * 8) = make_ushort4(vals[0], vals[1], vals[2], vals[3]);
    *(ushort4*)(out + (size_t)gid * 8 + 4) = make_ushort4(vals[4], vals[5], vals[6], vals[7]);
}

struct QkvPtrs { const float* w[9]; unsigned short* out; };

__global__ void k_packqkv(QkvPtrs P) {
    int layer = blockIdx.y;
    int gid = blockIdx.x * 256 + threadIdx.x;       // 0..49151
    int cb = gid >> 13, rem = gid & 8191;           // T*1024 = 8192
    int t = rem >> 10, rem2 = rem & 1023;
    int hl = rem2 >> 9, g = rem2 & 511;
    int r = ((g >> 6) << 4) | (g & 15);
    int kb = (g >> 4) & 3;
    int n = cb * 128 + r;
    int which = n >> 8, nl = n & 255;
    int k = t * 32 + kb * 8;
    const float* W = P.w[layer * 3 + which];
    unsigned short vals[8];
#pragma unroll
    for (int e = 0; e < 8; ++e) {
        float w = W[(size_t)(k + e) * 256 + nl];
        unsigned short h = f2bf(w);
        vals[e] = hl ? f2bf(w - bf2f(h)) : h;
    }
    size_t o = ((size_t)layer * 49152 + gid) * 8;
    *(ushort4*)(P.out + o) = make_ushort4(vals[0], vals[1], vals[2], vals[3]);
    *(ushort4*)(P.out + o + 4) = make_ushort4(vals[4], vals[5], vals[6], vals[7]);
}

struct BiasPtrs { const float* b[9]; float* dst; };

__global__ void k_bcat(BiasPtrs P) {
    int m = blockIdx.x;
    int layer = m / 3, which = m - layer * 3;
    P.dst[layer * 768 + which * 256 + (int)threadIdx.x] = P.b[m][threadIdx.x];
}

__global__ void k_cvt(const float* __restrict__ in, unsigned short* __restrict__ ob, int n4) {
    int i = blockIdx.x * 256 + threadIdx.x;
    if (i < n4) {
        float4 v = ((const float4*)in)[i];
        ushort4 o;
        o.x = f2bf(v.x); o.y = f2bf(v.y); o.z = f2bf(v.z); o.w = f2bf(v.w);
        ((ushort4*)ob)[i] = o;
    }
}

// ---------------- GCN propagate: y[d] = nd[d] * sum ewt[e] * x[src[e]] ----------------
// x fp8 e4m3 [NN,256] (256B rows); y bf16 [NN,256]. Lane-split (R10 structure):
// lanes 0-31 even-slot edges, 32-63 odd; each lane 8 cols via one 8B load.

__global__ void k_prop(const unsigned char* __restrict__ x8,
                       const int* __restrict__ row_ptr, const int* __restrict__ col_src,
                       const float* __restrict__ ewt, const float* __restrict__ ndv,
                       unsigned short* __restrict__ y) {
    int w = (int)((blockIdx.x * 256 + threadIdx.x) >> 6);
    if (w >= NN) return;
    int lane = threadIdx.x & 63;
    int half = lane >> 5;
    int c = (lane & 31) * 8;      // byte/dim offset
    float a[8] = {};
    int e0 = row_ptr[w], e1 = row_ptr[w + 1];
    int p = e0;
    for (; p + 4 <= e1; p += 4) {
        int pa = p + half, pb = p + 2 + half;
        int sa = col_src[pa], sb = col_src[pb];
        float wa = ewt[pa], wb = ewt[pb];
        uint2 va = *(const uint2*)(x8 + (size_t)sa * 256 + c);
        uint2 vb = *(const uint2*)(x8 + (size_t)sb * 256 + c);
        const unsigned char* ua = (const unsigned char*)&va;
        const unsigned char* ub = (const unsigned char*)&vb;
#pragma unroll
        for (int i = 0; i < 8; ++i)
            a[i] += wa * fp82f(ua[i]) + wb * fp82f(ub[i]);
    }
    if (p + 2 <= e1) {
        int pa = p + half;
        int sa = col_src[pa];
        float wa = ewt[pa];
        uint2 va = *(const uint2*)(x8 + (size_t)sa * 256 + c);
        const unsigned char* ua = (const unsigned char*)&va;
#pragma unroll
        for (int i = 0; i < 8; ++i) a[i] += wa * fp82f(ua[i]);
        p += 2;
    }
    if (p < e1 && half == 0) {
        int sa = col_src[p];
        float wa = ewt[p];
        uint2 va = *(const uint2*)(x8 + (size_t)sa * 256 + c);
        const unsigned char* ua = (const unsigned char*)&va;
#pragma unroll
        for (int i = 0; i < 8; ++i) a[i] += wa * fp82f(ua[i]);
    }
#pragma unroll
    for (int i = 0; i < 8; ++i) a[i] += __shfl_xor(a[i], 32);
    if (lane < 32) {
        float sc = ndv[w];
        unsigned short us[8];
#pragma unroll
        for (int i = 0; i < 8; ++i) us[i] = f2bf(a[i] * sc);
        *(uint4*)(y + (size_t)w * 256 + c) = *(const uint4*)us;
    }
}

// ---------------- edge attention ----------------
// QKV row (1280B, 640 shorts): Q bf16 [0,256) shorts; K fp8 [512,768) bytes;
// V bf16 [384,640) shorts. One wave per dst; 16-lane group = head; lane = 4 dims.
// Per edge per lane: 4B K-load + 8B V-load (768B/edge total). 4-edge unroll.
// Output: xo bf16 (xcat stride 768) + optional xprop fp8 [NN,256].

__global__ void k_attn(const unsigned short* __restrict__ QKV,
                       const int* __restrict__ row_ptr, const int* __restrict__ col_src,
                       unsigned short* __restrict__ xo, unsigned char* __restrict__ xprop) {
    int w = (int)((blockIdx.x * 256 + threadIdx.x) >> 6);
    if (w >= NN) return;
    const unsigned char* QKV8 = (const unsigned char*)QKV;
    int lane = threadIdx.x & 63;
    int c = lane * 4;
    const ushort4 qu = *(const ushort4*)(QKV + (size_t)w * 640 + c);
    float q0 = bf2f(qu.x), q1 = bf2f(qu.y), q2 = bf2f(qu.z), q3 = bf2f(qu.w);
    float v0 = 0, v1 = 0, v2 = 0, v3 = 0, z = 0;
    int e0 = row_ptr[w], e1 = row_ptr[w + 1];
    int p = e0;
#define EDGE_K(s_, t_)                                                         \
    {                                                                          \
        unsigned int k4 = *(const unsigned int*)(QKV8 + (size_t)(s_) * 1280 + 512 + c); \
        t_ = q0 * fp82f(k4 & 0xFF) + q1 * fp82f((k4 >> 8) & 0xFF) +            \
             q2 * fp82f((k4 >> 16) & 0xFF) + q3 * fp82f(k4 >> 24);             \
    }
#define EDGE_V(s_, sc_)                                                        \
    {                                                                          \
        ushort4 vu = *(const ushort4*)(QKV + (size_t)(s_) * 640 + 384 + c);    \
        v0 += (sc_) * bf2f(vu.x); v1 += (sc_) * bf2f(vu.y);                    \
        v2 += (sc_) * bf2f(vu.z); v3 += (sc_) * bf2f(vu.w);                    \
        z += (sc_);                                                            \
    }
    for (; p + 4 <= e1; p += 4) {
        int s0 = col_src[p], s1 = col_src[p + 1], s2 = col_src[p + 2], s3 = col_src[p + 3];
        float t0, t1, t2, t3;
        EDGE_K(s0, t0) EDGE_K(s1, t1) EDGE_K(s2, t2) EDGE_K(s3, t3)
        t0 += __shfl_xor(t0, 1); t1 += __shfl_xor(t1, 1); t2 += __shfl_xor(t2, 1); t3 += __shfl_xor(t3, 1);
        t0 += __shfl_xor(t0, 2); t1 += __shfl_xor(t1, 2); t2 += __shfl_xor(t2, 2); t3 += __shfl_xor(t3, 2);
        t0 += __shfl_xor(t0, 4); t1 += __shfl_xor(t1, 4); t2 += __shfl_xor(t2, 4); t3 += __shfl_xor(t3, 4);
        t0 += __shfl_xor(t0, 8); t1 += __shfl_xor(t1, 8); t2 += __shfl_xor(t2, 8); t3 += __shfl_xor(t3, 8);
        float sc0 = __expf(fminf(fmaxf(t0 * 0.125f, -10.f), 10.f));
        float sc1 = __expf(fminf(fmaxf(t1 * 0.125f, -10.f), 10.f));
        float sc2 = __expf(fminf(fmaxf(t2 * 0.125f, -10.f), 10.f));
        float sc3 = __expf(fminf(fmaxf(t3 * 0.125f, -10.f), 10.f));
        EDGE_V(s0, sc0) EDGE_V(s1, sc1) EDGE_V(s2, sc2) EDGE_V(s3, sc3)
    }
    for (; p < e1; ++p) {
        int s0 = col_src[p];
        float t0;
        EDGE_K(s0, t0)
        t0 += __shfl_xor(t0, 1);
        t0 += __shfl_xor(t0, 2);
        t0 += __shfl_xor(t0, 4);
        t0 += __shfl_xor(t0, 8);
        float sc0 = __expf(fminf(fmaxf(t0 * 0.125f, -10.f), 10.f));
        EDGE_V(s0, sc0)
    }
#undef EDGE_K
#undef EDGE_V
    float inv = 1.f / (z + 1e-6f);
    float o0 = v0 * inv, o1 = v1 * inv, o2 = v2 * inv, o3 = v3 * inv;
    ushort4 o;
    o.x = f2bf(o0); o.y = f2bf(o1); o.z = f2bf(o2); o.w = f2bf(o3);
    *(ushort4*)(xo + (size_t)w * 768 + c) = o;
    if (xprop) {
        unsigned int pk = (unsigned int)f2fp8(o0) | ((unsigned int)f2fp8(o1) << 8) |
                          ((unsigned int)f2fp8(o2) << 16) | ((unsigned int)f2fp8(o3) << 24);
        *(unsigned int*)(xprop + (size_t)w * 256 + c) = pk;
    }
}

// ---------------- bf16-A 2-term GEMM: out = relu(A @ W + b) ----------------
// A row-major bf16; B packed fragment-stream (R9 decoupled staging, 0 read
// conflicts). OMODE 0: bf16 out at ldc. OMODE 1: fp8 out [M,256] (bytes).
// OMODE 2: QKV row 1280B = Q bf16 [0,512)B | K fp8 [1024,1280)B | V bf16 [768,1280)... 
//          (shorts: Q [0,256), V [384,640); K bytes [512,768) of the 1280B row).

template <int NC, int OMODE>
__global__ __launch_bounds__(256, 3) void k_gemm(
    const unsigned short* __restrict__ A, int lda,
    const unsigned short* __restrict__ Bpk,
    const float* __restrict__ bias,
    void* __restrict__ Cout, int ldc, int M, int K) {
    const int P = (M + 127) >> 7;
    const int xcd = blockIdx.x & 7;
    const int j = blockIdx.x >> 3;
    const int ck = (P >> 3) + ((xcd < (P & 7)) ? 1 : 0);
    if (j >= NC * ck) return;
    const int brow = ((j / NC) * 8 + xcd) * 128;
    const int bcol = (j % NC) * 128;
    const int T = K >> 5;

    __shared__ unsigned short smem[24576];   // 48KB: 2 bufs x 12288 shorts

    const int tid = threadIdx.x;
    const int lane = tid & 63;
    const int wid = tid >> 6;
    const int wm = wid & 1, wn = wid >> 1;
    const int fr = lane & 15, kg = lane >> 4;

    const int r0 = tid >> 2, kb = tid & 3;
    const int gr0 = brow + r0, gr1 = gr0 + 64;
    const int ga0 = ((r0 >> 4) << 6) | (kb << 4) | (r0 & 15);
    const size_t aoff0 = (size_t)gr0 * lda + kb * 8;
    const size_t aoff1 = (size_t)gr1 * lda + kb * 8;
    const unsigned short* bstream = Bpk + (size_t)(bcol >> 7) * T * 8192;

    f32x4 acc[4][4] = {};
    uint4 av0, av1, bh0v, bh1v, bl0v, bl1v;

#define GLOAD(t_) {                                                            \
    const int k0_ = (t_) << 5;                                                 \
    av0 = make_uint4(0, 0, 0, 0); av1 = make_uint4(0, 0, 0, 0);                \
    if (gr0 < M) av0 = *(const uint4*)(A + aoff0 + k0_);                       \
    if (gr1 < M) av1 = *(const uint4*)(A + aoff1 + k0_);                       \
    const unsigned short* bs_ = bstream + (size_t)(t_) * 8192;                 \
    bh0v = *(const uint4*)(bs_ + tid * 8);                                     \
    bh1v = *(const uint4*)(bs_ + 2048 + tid * 8);                              \
    bl0v = *(const uint4*)(bs_ + 4096 + tid * 8);                              \
    bl1v = *(const uint4*)(bs_ + 6144 + tid * 8); }

#define LWRITE(b_) {                                                           \
    unsigned short* sb_ = smem + (b_) * 12288;                                 \
    *(uint4*)(sb_ + ga0 * 8) = av0;                                            \
    *(uint4*)(sb_ + ga0 * 8 + 2048) = av1;                                     \
    *(uint4*)(sb_ + 4096 + tid * 8) = bh0v;                                    \
    *(uint4*)(sb_ + 6144 + tid * 8) = bh1v;                                    \
    *(uint4*)(sb_ + 8192 + tid * 8) = bl0v;                                    \
    *(uint4*)(sb_ + 10240 + tid * 8) = bl1v; }

    GLOAD(0)
    LWRITE(0)
    for (int t = 0; t < T; ++t) {
        __syncthreads();
        if (t + 1 < T) { GLOAD(t + 1) }
        unsigned short* sb = smem + (t & 1) * 12288;
        s16x8 a[4], bh[4], bl[4];
#pragma unroll
        for (int f = 0; f < 4; ++f) {
            a[f]  = *(const s16x8*)(sb + ((wm * 4 + f) * 64 + lane) * 8);
            bh[f] = *(const s16x8*)(sb + 4096 + ((wn * 4 + f) * 64 + lane) * 8);
            bl[f] = *(const s16x8*)(sb + 8192 + ((wn * 4 + f) * 64 + lane) * 8);
        }
#pragma unroll
        for (int i = 0; i < 4; ++i)
#pragma unroll
            for (int jj = 0; jj < 4; ++jj) {
                acc[i][jj] = __builtin_amdgcn_mfma_f32_16x16x32_bf16(a[i], bh[jj], acc[i][jj], 0, 0, 0);
                acc[i][jj] = __builtin_amdgcn_mfma_f32_16x16x32_bf16(a[i], bl[jj], acc[i][jj], 0, 0, 0);
            }
        if (t + 1 < T) { LWRITE((t + 1) & 1) }
    }
#undef GLOAD
#undef LWRITE

#pragma unroll
    for (int i = 0; i < 4; ++i) {
#pragma unroll
        for (int jj = 0; jj < 4; ++jj) {
            int colG = bcol + wn * 64 + jj * 16 + fr;
            float bb = bias[colG];
#pragma unroll
            for (int r = 0; r < 4; ++r) {
                int row = brow + wm * 64 + i * 16 + kg * 4 + r;
                if (row < M) {
                    float v = fmaxf(acc[i][jj][r] + bb, 0.f);
                    if (OMODE == 0) {
                        ((unsigned short*)Cout)[(size_t)row * ldc + colG] = f2bf(v);
                    } else if (OMODE == 1) {
                        ((unsigned char*)Cout)[(size_t)row * 256 + colG] = f2fp8(v);
                    } else {
                        if (colG < 256)
                            ((unsigned short*)Cout)[(size_t)row * 640 + colG] = f2bf(v);
                        else if (colG < 512)
                            ((unsigned char*)Cout)[(size_t)row * 1280 + 512 + (colG - 256)] = f2fp8(v);
                        else
                            ((unsigned short*)Cout)[(size_t)row * 640 + 384 + (colG - 512)] = f2bf(v);
                    }
                }
            }
        }
    }
}

// ---------------- final row-dot + sigmoid ----------------

__global__ void k_final(const unsigned short* __restrict__ h2, const float* __restrict__ W3,
                        const float* __restrict__ b3, float* __restrict__ out) {
    int w = (int)((blockIdx.x * 256 + threadIdx.x) >> 6);
    if (w >= NN) return;
    int lane = threadIdx.x & 63;
    ushort4 hu = *(const ushort4*)(h2 + (size_t)w * 256 + lane * 4);
    float4 ww = *(const float4*)(W3 + lane * 4);
    float p = bf2f(hu.x) * ww.x + bf2f(hu.y) * ww.y + bf2f(hu.z) * ww.z + bf2f(hu.w) * ww.w;
    p += __shfl_xor(p, 1);
    p += __shfl_xor(p, 2);
    p += __shfl_xor(p, 4);
    p += __shfl_xor(p, 8);
    p += __shfl_xor(p, 16);
    p += __shfl_xor(p, 32);
    if (lane == 0) out[w] = 1.f / (1.f + __expf(-(p + b3[0])));
}

__global__ void k_sent(float* __restrict__ out) {
    int i = blockIdx.x * 256 + threadIdx.x;
    if (i < NN) out[i] = 0.5f;
}

// ---------------- launch ----------------

extern "C" void kernel_launch(void* const* d_in, const int* in_sizes, int n_in,
                              void* d_out, int out_size, void* d_ws, size_t ws_size,
                              hipStream_t stream) {
    const float* features = (const float*)d_in[0];
    const int* src = (const int*)d_in[1];
    const int* dst = (const int*)d_in[2];
    const float* Wm = (const float*)d_in[4];
    const float* bm = (const float*)d_in[5];
    const float* W1 = (const float*)d_in[24];
    const float* b1 = (const float*)d_in[25];
    const float* W2 = (const float*)d_in[26];
    const float* b2 = (const float*)d_in[27];
    const float* W3 = (const float*)d_in[28];
    const float* b3 = (const float*)d_in[29];
    float* out = (float*)d_out;

    char* ws = (char*)d_ws;
    size_t off = 0;
    auto alloc = [&](size_t b) -> void* {
        void* p = ws + off;
        off = (off + b + 255) & ~(size_t)255;
        return p;
    };

    int* deg_o = (int*)alloc(NN * 4);
    int* deg_i = (int*)alloc(NN * 4);
    int* row_ptr = (int*)alloc((NN + 1) * 4);
    int* cursor = (int*)alloc(NN * 4);
    int* col_src = (int*)alloc((size_t)NE * 4);
    float* ewt = (float*)alloc((size_t)NE * 4);
    float* ns = (float*)alloc(NN * 4);
    float* nd = (float*)alloc(NN * 4);
    int* incl = (int*)alloc(NN * 4);
    int* bsum = (int*)alloc(NBLK * 4);
    int* boff = (int*)alloc(NBLK * 4);

    unsigned short* Wmt = (unsigned short*)alloc((size_t)256 * 256 * 2 * 2);
    unsigned short* Wqkvt = (unsigned short*)alloc((size_t)3 * 768 * 256 * 2 * 2);
    unsigned short* W1t = (unsigned short*)alloc((size_t)512 * 768 * 2 * 2);
    unsigned short* W2t = (unsigned short*)alloc((size_t)256 * 512 * 2 * 2);
    float* bqkv = (float*)alloc(3 * 768 * 4);

    unsigned short* fbuf = (unsigned short*)alloc((size_t)NN * 256 * 2);     // 25.6 MB
    unsigned short* QKVb = (unsigned short*)alloc((size_t)NN * 640 * 2);     // 64 MB
    unsigned short* y = (unsigned short*)alloc((size_t)NN * 256 * 2);        // 25.6 MB
    unsigned short* xcat = (unsigned short*)alloc((size_t)NN * 768 * 2);     // 76.8 MB
    unsigned char* x0f8 = (unsigned char*)alloc((size_t)NN * 256);           // 12.8 MB
    unsigned char* xprop = (unsigned char*)alloc((size_t)NN * 256);          // 12.8 MB

    unsigned short* h1 = QKVb;    // [NN,512] bf16 = 51.2MB <= 64MB; QKVb dead after attn3
    unsigned short* h2 = y;       // [NN,256]; y dead after layer-3 QKV gemm

    (void)in_sizes; (void)n_in; (void)out_size;

    if (off > ws_size) {
        k_sent<<<(NN + 255) / 256, 256, 0, stream>>>(out);
        return;
    }

    hipMemsetAsync(deg_o, 0, (size_t)((char*)deg_i - (char*)deg_o) + NN * 4, stream);
    k_deg<<<(NE + 255) / 256, 256, 0, stream>>>(src, dst, deg_o, deg_i);
    k_scanA<<<NBLK, 256, 0, stream>>>(deg_i, incl, bsum);
    k_scanB<<<1, 256, 0, stream>>>(bsum, boff, row_ptr);
    k_scanC<<<NBLK, 256, 0, stream>>>(deg_o, deg_i, incl, boff, row_ptr, cursor, ns, nd);
    k_fill<<<(NE + 255) / 256, 256, 0, stream>>>(src, dst, ns, cursor, col_src, ewt);

    QkvPtrs qp;
    BiasPtrs bp;
    for (int l = 0; l < 3; ++l)
        for (int m = 0; m < 3; ++m) {
            qp.w[l * 3 + m] = (const float*)d_in[6 + l * 6 + m * 2];
            bp.b[l * 3 + m] = (const float*)d_in[7 + l * 6 + m * 2];
        }
    qp.out = Wqkvt;
    bp.dst = bqkv;
    k_packqkv<<<dim3(192, 3), 256, 0, stream>>>(qp);
    k_bcat<<<9, 256, 0, stream>>>(bp);
    k_packw<<<64, 256, 0, stream>>>(Wm, Wmt, 256, 256, 16384);
    k_packw<<<384, 256, 0, stream>>>(W1, W1t, 768, 512, 98304);
    k_packw<<<128, 256, 0, stream>>>(W2, W2t, 512, 256, 32768);

    k_cvt<<<(NN * 64 + 255) / 256, 256, 0, stream>>>(features, fbuf, NN * 64);

    const int P8 = ((NN + 127) / 128 + 7) / 8;  // 49

    // x0 (fp8) = relu(features @ Wm + bm)
    k_gemm<2, 1><<<8 * 2 * P8, 256, 0, stream>>>(fbuf, 256, Wmt, bm, x0f8, 0, NN, 256);

    const unsigned char* xin = x0f8;
    for (int l = 0; l < 3; ++l) {
        k_prop<<<12500, 256, 0, stream>>>(xin, row_ptr, col_src, ewt, nd, y);
        k_gemm<6, 2><<<8 * 6 * P8, 256, 0, stream>>>(y, 256, Wqkvt + (size_t)l * 393216,
                                                     bqkv + l * 768, QKVb, 0, NN, 256);
        k_attn<<<12500, 256, 0, stream>>>(QKVb, row_ptr, col_src, xcat + 256 * l,
                                          l < 2 ? xprop : nullptr);
        xin = xprop;
    }

    // MLP head
    k_gemm<4, 0><<<8 * 4 * P8, 256, 0, stream>>>(xcat, 768, W1t, b1, h1, 512, NN, 768);
    k_gemm<2, 0><<<8 * 2 * P8, 256, 0, stream>>>(h1, 512, W2t, b2, h2, 256, NN, 512);
    k_final<<<12500, 256, 0, stream>>>(h2, W3, b3, out);
}